// Round 1
// baseline (6122.903 us; speedup 1.0000x reference)
//
#include <hip/hip_runtime.h>

#define NEG_ATT 0.2f
#define NEG_ACT 0.01f

// ---------- GEMM: C[M,N] = X[M,K] @ W[K,N], fp32. BM=64,BN=64,BK=16, 256 thr, 4x4 micro
__global__ __launch_bounds__(256) void gemm_f32(const float* __restrict__ X,
    const float* __restrict__ W, float* __restrict__ C, int M, int N, int K) {
  const int BM = 64, BN = 64, BK = 16, TM = 4, TN = 4;
  __shared__ float sX[BK][BM + 1];
  __shared__ float sW[BK][BN + 1];
  int bm = blockIdx.y * BM, bn = blockIdx.x * BN;
  int tid = threadIdx.x;
  int tr = tid >> 4, tc = tid & 15;
  float acc[TM][TN];
#pragma unroll
  for (int i = 0; i < TM; i++)
#pragma unroll
    for (int j = 0; j < TN; j++) acc[i][j] = 0.f;

  for (int k0 = 0; k0 < K; k0 += BK) {
#pragma unroll
    for (int i = tid; i < BM * BK; i += 256) {
      int r = i >> 4, c = i & 15;
      int gr = bm + r;
      sX[c][r] = (gr < M) ? X[(size_t)gr * K + k0 + c] : 0.f;
    }
#pragma unroll
    for (int i = tid; i < BK * BN; i += 256) {
      int r = i >> 6, c = i & 63;
      sW[r][c] = W[(size_t)(k0 + r) * N + bn + c];
    }
    __syncthreads();
#pragma unroll
    for (int kk = 0; kk < BK; kk++) {
      float xr[TM], wr[TN];
#pragma unroll
      for (int i = 0; i < TM; i++) xr[i] = sX[kk][tr * TM + i];
#pragma unroll
      for (int j = 0; j < TN; j++) wr[j] = sW[kk][tc * TN + j];
#pragma unroll
      for (int i = 0; i < TM; i++)
#pragma unroll
        for (int j = 0; j < TN; j++) acc[i][j] += xr[i] * wr[j];
    }
    __syncthreads();
  }
#pragma unroll
  for (int i = 0; i < TM; i++) {
    int row = bm + tr * TM + i;
    if (row < M) {
#pragma unroll
      for (int j = 0; j < TN; j++) C[(size_t)row * N + bn + tc * TN + j] = acc[i][j];
    }
  }
}

// ---------- GEMM N=16 (layer 3): C[M,16] = X[M,256] @ W[256,16]
__global__ __launch_bounds__(256) void gemm_n16(const float* __restrict__ X,
    const float* __restrict__ W, float* __restrict__ C, int M) {
  const int K = 256;
  __shared__ float sW[K * 16];        // 16 KB
  __shared__ float sX[16][K + 1];     // 16.06 KB
  int tid = threadIdx.x;
  int tr = tid >> 4, tc = tid & 15;
  int bm = blockIdx.x * 16;
  for (int i = tid; i < K * 16; i += 256) sW[i] = W[i];
  for (int i = tid; i < 16 * K; i += 256) {
    int r = i >> 8, c = i & 255;
    int gr = bm + r;
    sX[r][c] = (gr < M) ? X[(size_t)gr * K + c] : 0.f;
  }
  __syncthreads();
  float acc = 0.f;
#pragma unroll 8
  for (int k = 0; k < K; k++) acc += sX[tr][k] * sW[k * 16 + tc];
  int row = bm + tr;
  if (row < M) C[(size_t)row * 16 + tc] = acc;
}

// ---------- per-node attention scores: s_src[n]=h[n]·a_s, s_dst[n]=h[n]·a_d
__global__ __launch_bounds__(256) void row_dots(const float* __restrict__ H,
    const float* __restrict__ a_s, const float* __restrict__ a_d,
    float* __restrict__ s_src, float* __restrict__ s_dst, int Nn, int F) {
  int node = blockIdx.x * 4 + (threadIdx.x >> 6);
  int lane = threadIdx.x & 63;
  if (node >= Nn) return;
  float ss = 0.f, sd = 0.f;
  for (int c = lane; c < F; c += 64) {
    float h = H[(size_t)node * F + c];
    ss += h * a_s[c];
    sd += h * a_d[c];
  }
#pragma unroll
  for (int off = 32; off > 0; off >>= 1) {
    ss += __shfl_down(ss, off);
    sd += __shfl_down(sd, off);
  }
  if (lane == 0) { s_src[node] = ss; s_dst[node] = sd; }
}

__device__ __forceinline__ unsigned flip_f32(float f) {
  unsigned u = __float_as_uint(f);
  return (u & 0x80000000u) ? ~u : (u | 0x80000000u);
}
__device__ __forceinline__ float unflip_f32(unsigned k) {
  return (k & 0x80000000u) ? __uint_as_float(k & 0x7FFFFFFFu) : __uint_as_float(~k);
}

// ---------- per-edge score + segment max (flipped-uint atomicMax)
__global__ __launch_bounds__(256) void edge_max(const float* __restrict__ s_src,
    const float* __restrict__ s_dst, const int* __restrict__ src,
    const int* __restrict__ dst, unsigned* __restrict__ mflip, int E) {
  int e = blockIdx.x * 256 + threadIdx.x;
  if (e >= E) return;
  float v = s_src[src[e]] + s_dst[dst[e]];
  v = v > 0.f ? v : v * NEG_ATT;
  atomicMax(&mflip[dst[e]], flip_f32(v));
}

// ---------- per-edge exp + segment sum
__global__ __launch_bounds__(256) void edge_exp(const float* __restrict__ s_src,
    const float* __restrict__ s_dst, const int* __restrict__ src,
    const int* __restrict__ dst, const unsigned* __restrict__ mflip,
    float* __restrict__ ex, float* __restrict__ denom, int E) {
  int e = blockIdx.x * 256 + threadIdx.x;
  if (e >= E) return;
  int d = dst[e];
  float v = s_src[src[e]] + s_dst[d];
  v = v > 0.f ? v : v * NEG_ATT;
  float m = unflip_f32(mflip[d]);
  float x = expf(v - m);
  ex[e] = x;
  atomicAdd(&denom[d], x);
}

// ---------- aggregation: out[dst] += (ex/denom[dst]) * h[src], F/4 lanes per edge
template <int F>
__global__ __launch_bounds__(256) void edge_agg(const float* __restrict__ H,
    const float* __restrict__ ex, const float* __restrict__ denom,
    const int* __restrict__ src, const int* __restrict__ dst,
    float* __restrict__ out, int E) {
  const int LPE = F / 4;
  long long gid = (long long)blockIdx.x * 256 + threadIdx.x;
  if (gid >= (long long)E * LPE) return;
  int e = (int)(gid / LPE);
  int c4 = ((int)gid & (LPE - 1)) * 4;
  int s = src[e], d = dst[e];
  float alpha = ex[e] / denom[d];
  const float4 hv = *(const float4*)&H[(size_t)s * F + c4];
  float* o = &out[(size_t)d * F + c4];
  atomicAdd(o + 0, alpha * hv.x);
  atomicAdd(o + 1, alpha * hv.y);
  atomicAdd(o + 2, alpha * hv.z);
  atomicAdd(o + 3, alpha * hv.w);
}

// ---------- bias + leaky (slope=1 -> bias only)
__global__ __launch_bounds__(256) void bias_act(float* __restrict__ out,
    const float* __restrict__ b, long long total, int Fmask, float slope) {
  long long i = (long long)blockIdx.x * 256 + threadIdx.x;
  if (i >= total) return;
  float v = out[i] + b[(int)i & Fmask];
  out[i] = v > 0.f ? v : v * slope;
}

// ---------- gather first node of each graph
__global__ __launch_bounds__(256) void gather_out(const float* __restrict__ h3,
    const int* __restrict__ batch, float* __restrict__ out, int Nn) {
  long long i = (long long)blockIdx.x * 256 + threadIdx.x;
  if (i >= (long long)Nn * 16) return;
  int node = (int)(i >> 4), c = (int)i & 15;
  bool sel = (node == 0) || (batch[node] != batch[node - 1]);
  if (sel) out[(size_t)batch[node] * 16 + c] = h3[(size_t)node * 16 + c];
}

extern "C" void kernel_launch(void* const* d_in, const int* in_sizes, int n_in,
                              void* d_out, int out_size, void* d_ws, size_t ws_size,
                              hipStream_t stream) {
  const float* x   = (const float*)d_in[0];
  const int* src   = (const int*)d_in[1];
  const int* dst   = (const int*)d_in[2];
  const int* batch = (const int*)d_in[3];
  const float* W1 = (const float*)d_in[4];
  const float* as1 = (const float*)d_in[5];
  const float* ad1 = (const float*)d_in[6];
  const float* b1 = (const float*)d_in[7];
  const float* W2 = (const float*)d_in[8];
  const float* as2 = (const float*)d_in[9];
  const float* ad2 = (const float*)d_in[10];
  const float* b2 = (const float*)d_in[11];
  const float* W3 = (const float*)d_in[12];
  const float* as3 = (const float*)d_in[13];
  const float* ad3 = (const float*)d_in[14];
  const float* b3 = (const float*)d_in[15];

  const int N = in_sizes[3];   // 50000 nodes
  const int E = in_sizes[1];   // 800000 edges

  char* ws = (char*)d_ws;
  size_t off = 0;
  auto alloc = [&](size_t bytes) -> void* {
    void* p = ws + off;
    off = (off + bytes + 255) & ~(size_t)255;
    return p;
  };
  float* A      = (float*)alloc((size_t)N * 256 * 4);  // h (transformed features)
  float* B      = (float*)alloc((size_t)N * 256 * 4);  // aggregated output / next input
  float* ssrc   = (float*)alloc((size_t)N * 4);
  float* sdst   = (float*)alloc((size_t)N * 4);
  unsigned* mfl = (unsigned*)alloc((size_t)N * 4);
  float* denom  = (float*)alloc((size_t)N * 4);
  float* ex     = (float*)alloc((size_t)E * 4);
  float* h3     = (float*)alloc((size_t)N * 16 * 4);
  float* out3   = (float*)alloc((size_t)N * 16 * 4);
  (void)ws_size;

  dim3 blk(256);
  int mblocks = (N + 63) / 64;

  auto attention = [&](const float* H, int F, const float* a_s, const float* a_d,
                       float* outbuf, const float* bias, float slope) {
    row_dots<<<(N + 3) / 4, blk, 0, stream>>>(H, a_s, a_d, ssrc, sdst, N, F);
    hipMemsetAsync(mfl, 0, (size_t)N * 4, stream);
    hipMemsetAsync(denom, 0, (size_t)N * 4, stream);
    edge_max<<<(E + 255) / 256, blk, 0, stream>>>(ssrc, sdst, src, dst, mfl, E);
    edge_exp<<<(E + 255) / 256, blk, 0, stream>>>(ssrc, sdst, src, dst, mfl, ex, denom, E);
    hipMemsetAsync(outbuf, 0, (size_t)N * F * 4, stream);
    long long tot = (long long)E * (F / 4);
    if (F == 256)
      edge_agg<256><<<(int)((tot + 255) / 256), blk, 0, stream>>>(H, ex, denom, src, dst, outbuf, E);
    else
      edge_agg<16><<<(int)((tot + 255) / 256), blk, 0, stream>>>(H, ex, denom, src, dst, outbuf, E);
    long long total = (long long)N * F;
    bias_act<<<(int)((total + 255) / 256), blk, 0, stream>>>(outbuf, bias, total, F - 1, slope);
  };

  // ---- layer 1: A = x @ W1   (K=128, N=256)
  gemm_f32<<<dim3(4, mblocks), blk, 0, stream>>>(x, W1, A, N, 256, 128);
  attention(A, 256, as1, ad1, B, b1, NEG_ACT);

  // ---- layer 2: A = B @ W2   (K=256, N=256)
  gemm_f32<<<dim3(4, mblocks), blk, 0, stream>>>(B, W2, A, N, 256, 256);
  attention(A, 256, as2, ad2, B, b2, NEG_ACT);

  // ---- layer 3: h3 = B @ W3  (K=256, N=16)
  gemm_n16<<<(N + 15) / 16, blk, 0, stream>>>(B, W3, h3, N);
  attention(h3, 16, as3, ad3, out3, b3, 1.0f);

  gather_out<<<(int)(((long long)N * 16 + 255) / 256), blk, 0, stream>>>(out3, batch, (float*)d_out, N);
}

// Round 2
// 801.026 us; speedup vs baseline: 7.6438x; 7.6438x over previous
//
#include <hip/hip_runtime.h>

#define NEG_ATT 0.2f
#define NEG_ACT 0.01f

// ---------- GEMM: C[M,N] = X[M,K] @ W[K,N], fp32. BM=64,BN=64,BK=16, 256 thr, 4x4 micro
__global__ __launch_bounds__(256) void gemm_f32(const float* __restrict__ X,
    const float* __restrict__ W, float* __restrict__ C, int M, int N, int K) {
  const int BM = 64, BN = 64, BK = 16, TM = 4, TN = 4;
  __shared__ float sX[BK][BM + 1];
  __shared__ float sW[BK][BN + 1];
  int bm = blockIdx.y * BM, bn = blockIdx.x * BN;
  int tid = threadIdx.x;
  int tr = tid >> 4, tc = tid & 15;
  float acc[TM][TN];
#pragma unroll
  for (int i = 0; i < TM; i++)
#pragma unroll
    for (int j = 0; j < TN; j++) acc[i][j] = 0.f;

  for (int k0 = 0; k0 < K; k0 += BK) {
#pragma unroll
    for (int i = tid; i < BM * BK; i += 256) {
      int r = i >> 4, c = i & 15;
      int gr = bm + r;
      sX[c][r] = (gr < M) ? X[(size_t)gr * K + k0 + c] : 0.f;
    }
#pragma unroll
    for (int i = tid; i < BK * BN; i += 256) {
      int r = i >> 6, c = i & 63;
      sW[r][c] = W[(size_t)(k0 + r) * N + bn + c];
    }
    __syncthreads();
#pragma unroll
    for (int kk = 0; kk < BK; kk++) {
      float xr[TM], wr[TN];
#pragma unroll
      for (int i = 0; i < TM; i++) xr[i] = sX[kk][tr * TM + i];
#pragma unroll
      for (int j = 0; j < TN; j++) wr[j] = sW[kk][tc * TN + j];
#pragma unroll
      for (int i = 0; i < TM; i++)
#pragma unroll
        for (int j = 0; j < TN; j++) acc[i][j] += xr[i] * wr[j];
    }
    __syncthreads();
  }
#pragma unroll
  for (int i = 0; i < TM; i++) {
    int row = bm + tr * TM + i;
    if (row < M) {
#pragma unroll
      for (int j = 0; j < TN; j++) C[(size_t)row * N + bn + tc * TN + j] = acc[i][j];
    }
  }
}

// ---------- GEMM N=16 (layer 3): C[M,16] = X[M,256] @ W[256,16]
__global__ __launch_bounds__(256) void gemm_n16(const float* __restrict__ X,
    const float* __restrict__ W, float* __restrict__ C, int M) {
  const int K = 256;
  __shared__ float sW[K * 16];
  __shared__ float sX[16][K + 1];
  int tid = threadIdx.x;
  int tr = tid >> 4, tc = tid & 15;
  int bm = blockIdx.x * 16;
  for (int i = tid; i < K * 16; i += 256) sW[i] = W[i];
  for (int i = tid; i < 16 * K; i += 256) {
    int r = i >> 8, c = i & 255;
    int gr = bm + r;
    sX[r][c] = (gr < M) ? X[(size_t)gr * K + c] : 0.f;
  }
  __syncthreads();
  float acc = 0.f;
#pragma unroll 8
  for (int k = 0; k < K; k++) acc += sX[tr][k] * sW[k * 16 + tc];
  int row = bm + tr;
  if (row < M) C[(size_t)row * 16 + tc] = acc;
}

// ---------- per-node attention scores: s_src[n]=h[n]·a_s, s_dst[n]=h[n]·a_d
__global__ __launch_bounds__(256) void row_dots(const float* __restrict__ H,
    const float* __restrict__ a_s, const float* __restrict__ a_d,
    float* __restrict__ s_src, float* __restrict__ s_dst, int Nn, int F) {
  int node = blockIdx.x * 4 + (threadIdx.x >> 6);
  int lane = threadIdx.x & 63;
  if (node >= Nn) return;
  float ss = 0.f, sd = 0.f;
  for (int c = lane; c < F; c += 64) {
    float h = H[(size_t)node * F + c];
    ss += h * a_s[c];
    sd += h * a_d[c];
  }
#pragma unroll
  for (int off = 32; off > 0; off >>= 1) {
    ss += __shfl_down(ss, off);
    sd += __shfl_down(sd, off);
  }
  if (lane == 0) { s_src[node] = ss; s_dst[node] = sd; }
}

// ---------- CSR build: histogram of dst
__global__ __launch_bounds__(256) void deg_hist(const int* __restrict__ dst,
    int* __restrict__ deg, int E) {
  int e = blockIdx.x * 256 + threadIdx.x;
  if (e >= E) return;
  atomicAdd(&deg[dst[e]], 1);
}

// ---------- single-block exclusive scan: rowptr[0..N] from deg[0..N-1]
__global__ __launch_bounds__(1024) void scan_rowptr(const int* __restrict__ deg,
    int* __restrict__ rowptr, int N) {
  __shared__ int sdata[1024];
  __shared__ int carry;
  int tid = threadIdx.x;
  if (tid == 0) carry = 0;
  __syncthreads();
  for (int base = 0; base < N; base += 1024) {
    int idx = base + tid;
    int v = (idx < N) ? deg[idx] : 0;
    sdata[tid] = v;
    __syncthreads();
    for (int off = 1; off < 1024; off <<= 1) {
      int t = (tid >= off) ? sdata[tid - off] : 0;
      __syncthreads();
      sdata[tid] += t;
      __syncthreads();
    }
    int incl = sdata[tid];
    if (idx < N) rowptr[idx] = carry + incl - v;
    __syncthreads();
    if (tid == 1023) carry += sdata[1023];
    __syncthreads();
  }
  if (tid == 0) rowptr[N] = carry;
}

// ---------- CSR placement
__global__ __launch_bounds__(256) void csr_place(const int* __restrict__ src,
    const int* __restrict__ dst, const int* __restrict__ rowptr,
    int* __restrict__ cnt, int* __restrict__ csr_src, int E) {
  int e = blockIdx.x * 256 + threadIdx.x;
  if (e >= E) return;
  int d = dst[e];
  int pos = rowptr[d] + atomicAdd(&cnt[d], 1);
  csr_src[pos] = src[e];
}

// ---------- per-node softmax over in-edges -> alpha (CSR order), 1 wave/node
__global__ __launch_bounds__(256) void attn_node(const float* __restrict__ ssrc,
    const float* __restrict__ sdst, const int* __restrict__ rowptr,
    const int* __restrict__ csr_src, float* __restrict__ alpha, int N) {
  int node = blockIdx.x * 4 + (threadIdx.x >> 6);
  int lane = threadIdx.x & 63;
  if (node >= N) return;
  int r0 = rowptr[node], r1 = rowptr[node + 1];
  if (r0 == r1) return;
  float sd = sdst[node];
  float m = -1e30f;
  for (int i = r0 + lane; i < r1; i += 64) {
    float v = ssrc[csr_src[i]] + sd;
    v = v > 0.f ? v : v * NEG_ATT;
    alpha[i] = v;
    m = fmaxf(m, v);
  }
#pragma unroll
  for (int off = 32; off > 0; off >>= 1) m = fmaxf(m, __shfl_xor(m, off));
  float s = 0.f;
  for (int i = r0 + lane; i < r1; i += 64) {
    float x = expf(alpha[i] - m);
    alpha[i] = x;
    s += x;
  }
#pragma unroll
  for (int off = 32; off > 0; off >>= 1) s += __shfl_xor(s, off);
  float inv = 1.f / s;
  for (int i = r0 + lane; i < r1; i += 64) alpha[i] *= inv;
}

// ---------- gather aggregation F=256: one block per node, thread=channel
__global__ __launch_bounds__(256) void agg256(const float* __restrict__ H,
    const int* __restrict__ rowptr, const int* __restrict__ csr_src,
    const float* __restrict__ alpha, const float* __restrict__ b,
    float* __restrict__ out, float slope) {
  __shared__ int s_src[64];
  __shared__ float s_al[64];
  int node = blockIdx.x;
  int c = threadIdx.x;
  int r0 = rowptr[node], r1 = rowptr[node + 1];
  float a0 = 0.f, a1 = 0.f, a2 = 0.f, a3 = 0.f;
  for (int base = r0; base < r1; base += 64) {
    int nthis = min(64, r1 - base);
    if (c < nthis) { s_src[c] = csr_src[base + c]; s_al[c] = alpha[base + c]; }
    __syncthreads();
    int j = 0;
    for (; j + 4 <= nthis; j += 4) {
      float w0 = s_al[j], w1 = s_al[j + 1], w2 = s_al[j + 2], w3 = s_al[j + 3];
      float h0 = H[(size_t)s_src[j] * 256 + c];
      float h1 = H[(size_t)s_src[j + 1] * 256 + c];
      float h2 = H[(size_t)s_src[j + 2] * 256 + c];
      float h3v = H[(size_t)s_src[j + 3] * 256 + c];
      a0 += w0 * h0; a1 += w1 * h1; a2 += w2 * h2; a3 += w3 * h3v;
    }
    for (; j < nthis; j++) a0 += s_al[j] * H[(size_t)s_src[j] * 256 + c];
    __syncthreads();
  }
  float v = (a0 + a1) + (a2 + a3) + b[c];
  out[(size_t)node * 256 + c] = v > 0.f ? v : v * slope;
}

// ---------- gather aggregation F=16: 16 nodes per block (no activation, slope=1)
__global__ __launch_bounds__(256) void agg16(const float* __restrict__ H,
    const int* __restrict__ rowptr, const int* __restrict__ csr_src,
    const float* __restrict__ alpha, const float* __restrict__ b,
    float* __restrict__ out, int N) {
  int node = blockIdx.x * 16 + (threadIdx.x >> 4);
  int c = threadIdx.x & 15;
  if (node >= N) return;
  int r0 = rowptr[node], r1 = rowptr[node + 1];
  float acc = 0.f;
  for (int i = r0; i < r1; i++) acc += alpha[i] * H[(size_t)csr_src[i] * 16 + c];
  out[(size_t)node * 16 + c] = acc + b[c];
}

// ---------- gather first node of each graph
__global__ __launch_bounds__(256) void gather_out(const float* __restrict__ h3,
    const int* __restrict__ batch, float* __restrict__ out, int Nn) {
  long long i = (long long)blockIdx.x * 256 + threadIdx.x;
  if (i >= (long long)Nn * 16) return;
  int node = (int)(i >> 4), c = (int)i & 15;
  bool sel = (node == 0) || (batch[node] != batch[node - 1]);
  if (sel) out[(size_t)batch[node] * 16 + c] = h3[(size_t)node * 16 + c];
}

extern "C" void kernel_launch(void* const* d_in, const int* in_sizes, int n_in,
                              void* d_out, int out_size, void* d_ws, size_t ws_size,
                              hipStream_t stream) {
  const float* x   = (const float*)d_in[0];
  const int* src   = (const int*)d_in[1];
  const int* dst   = (const int*)d_in[2];
  const int* batch = (const int*)d_in[3];
  const float* W1 = (const float*)d_in[4];
  const float* as1 = (const float*)d_in[5];
  const float* ad1 = (const float*)d_in[6];
  const float* b1 = (const float*)d_in[7];
  const float* W2 = (const float*)d_in[8];
  const float* as2 = (const float*)d_in[9];
  const float* ad2 = (const float*)d_in[10];
  const float* b2 = (const float*)d_in[11];
  const float* W3 = (const float*)d_in[12];
  const float* as3 = (const float*)d_in[13];
  const float* ad3 = (const float*)d_in[14];
  const float* b3 = (const float*)d_in[15];

  const int N = in_sizes[3];   // 50000 nodes
  const int E = in_sizes[1];   // 800000 edges

  char* ws = (char*)d_ws;
  size_t off = 0;
  auto alloc = [&](size_t bytes) -> void* {
    void* p = ws + off;
    off = (off + bytes + 255) & ~(size_t)255;
    return p;
  };
  float* A      = (float*)alloc((size_t)N * 256 * 4);
  float* B      = (float*)alloc((size_t)N * 256 * 4);
  float* ssrc   = (float*)alloc((size_t)N * 4);
  float* sdst   = (float*)alloc((size_t)N * 4);
  float* alpha  = (float*)alloc((size_t)E * 4);
  int* deg      = (int*)alloc((size_t)N * 4);
  int* rowptr   = (int*)alloc((size_t)(N + 1) * 4);
  int* cnt      = (int*)alloc((size_t)N * 4);
  int* csr_src  = (int*)alloc((size_t)E * 4);
  float* h3     = (float*)alloc((size_t)N * 16 * 4);
  float* out3   = (float*)alloc((size_t)N * 16 * 4);
  (void)ws_size;

  dim3 blk(256);
  int eblocks = (E + 255) / 256;
  int mblocks = (N + 63) / 64;

  // ---- CSR build (by dst)
  hipMemsetAsync(deg, 0, (size_t)N * 4, stream);
  deg_hist<<<eblocks, blk, 0, stream>>>(dst, deg, E);
  scan_rowptr<<<1, 1024, 0, stream>>>(deg, rowptr, N);
  hipMemsetAsync(cnt, 0, (size_t)N * 4, stream);
  csr_place<<<eblocks, blk, 0, stream>>>(src, dst, rowptr, cnt, csr_src, E);

  auto attention256 = [&](const float* H, const float* a_s, const float* a_d,
                          float* outbuf, const float* bias, float slope) {
    row_dots<<<(N + 3) / 4, blk, 0, stream>>>(H, a_s, a_d, ssrc, sdst, N, 256);
    attn_node<<<(N + 3) / 4, blk, 0, stream>>>(ssrc, sdst, rowptr, csr_src, alpha, N);
    agg256<<<N, blk, 0, stream>>>(H, rowptr, csr_src, alpha, bias, outbuf, slope);
  };

  // ---- layer 1: A = x @ W1   (K=128, N=256)
  gemm_f32<<<dim3(4, mblocks), blk, 0, stream>>>(x, W1, A, N, 256, 128);
  attention256(A, as1, ad1, B, b1, NEG_ACT);

  // ---- layer 2: A = B @ W2   (K=256, N=256)
  gemm_f32<<<dim3(4, mblocks), blk, 0, stream>>>(B, W2, A, N, 256, 256);
  attention256(A, as2, ad2, B, b2, NEG_ACT);

  // ---- layer 3: h3 = B @ W3  (K=256, N=16)
  gemm_n16<<<(N + 15) / 16, blk, 0, stream>>>(B, W3, h3, N);
  row_dots<<<(N + 3) / 4, blk, 0, stream>>>(h3, as3, ad3, ssrc, sdst, N, 16);
  attn_node<<<(N + 3) / 4, blk, 0, stream>>>(ssrc, sdst, rowptr, csr_src, alpha, N);
  agg16<<<(N + 15) / 16, blk, 0, stream>>>(h3, rowptr, csr_src, alpha, b3, out3, N);

  gather_out<<<(int)(((long long)N * 16 + 255) / 256), blk, 0, stream>>>(out3, batch, (float*)d_out, N);
}

// Round 13
// 608.511 us; speedup vs baseline: 10.0621x; 1.3164x over previous
//
#include <hip/hip_runtime.h>

#define NEG_ATT 0.2f
#define NEG_ACT 0.01f

typedef short s16x8 __attribute__((ext_vector_type(8)));
typedef float f32x4 __attribute__((ext_vector_type(4)));

__device__ __forceinline__ short f2bf_rn(float f) {
  unsigned u = __float_as_uint(f);
  unsigned r = (u + 0x7FFFu + ((u >> 16) & 1u)) >> 16;
  return (short)r;
}
__device__ __forceinline__ float bf2f(short h) {
  return __uint_as_float(((unsigned)(unsigned short)h) << 16);
}

// ---------- convert X fp32 [M][K] -> Xb bf16 [M][2K] (hi cols 0..K-1, lo K..2K-1)
__global__ __launch_bounds__(256) void conv_x(const float* __restrict__ X,
    short* __restrict__ Xb, int M, int K) {
  long long gid = (long long)blockIdx.x * 256 + threadIdx.x;
  long long tot = (long long)M * (K / 4);
  if (gid >= tot) return;
  int row = (int)(gid / (K / 4));
  int c4 = ((int)(gid % (K / 4))) * 4;
  float4 v = *(const float4*)&X[(size_t)row * K + c4];
  short4 hi, lo;
  hi.x = f2bf_rn(v.x); lo.x = f2bf_rn(v.x - bf2f(hi.x));
  hi.y = f2bf_rn(v.y); lo.y = f2bf_rn(v.y - bf2f(hi.y));
  hi.z = f2bf_rn(v.z); lo.z = f2bf_rn(v.z - bf2f(hi.z));
  hi.w = f2bf_rn(v.w); lo.w = f2bf_rn(v.w - bf2f(hi.w));
  *(short4*)&Xb[(size_t)row * 2 * K + c4] = hi;
  *(short4*)&Xb[(size_t)row * 2 * K + K + c4] = lo;
}

// ---------- convert+transpose W fp32 [K][N] -> Wtb bf16 [N][2K]
__global__ __launch_bounds__(256) void conv_w(const float* __restrict__ W,
    short* __restrict__ Wtb, int K, int N) {
  int gid = blockIdx.x * 256 + threadIdx.x;
  if (gid >= K * N) return;
  int k = gid / N, n = gid % N;
  float v = W[(size_t)k * N + n];
  short hi = f2bf_rn(v);
  short lo = f2bf_rn(v - bf2f(hi));
  Wtb[(size_t)n * 2 * K + k] = hi;
  Wtb[(size_t)n * 2 * K + K + k] = lo;
}

// ---------- split-bf16 MFMA GEMM: C[M,N] = X[M,K] @ W[K,N] (~fp32 precision)
// Xb [M][2K] (hi|lo), Wtb [N][2K] (hi|lo). BM=BN=64, BK=32, 4 waves 2x2, wave=32x32.
__global__ __launch_bounds__(256) void gemm_bf16split(const short* __restrict__ Xb,
    const short* __restrict__ Wtb, float* __restrict__ C, int M, int N, int K) {
  __shared__ short sA[2][64][40];  // [hi/lo][row][k] pad->40 (2-way bank, free)
  __shared__ short sB[2][64][40];  // [hi/lo][col][k]
  const int K2 = 2 * K;
  int tid = threadIdx.x;
  int w = tid >> 6, l = tid & 63;
  int wr = w >> 1, wc = w & 1;
  int bm = blockIdx.y * 64, bn = blockIdx.x * 64;
  int sr = tid >> 2, sq = (tid & 3) * 8;   // staging: row, k-segment

  f32x4 acc[2][2];
#pragma unroll
  for (int i = 0; i < 2; i++)
#pragma unroll
    for (int j = 0; j < 2; j++) acc[i][j] = (f32x4)0.f;

  int lrow = l & 15, k8 = (l >> 4) * 8;

  for (int k0 = 0; k0 < K; k0 += 32) {
    {
      int g = bm + sr;
      s16x8 hi = (s16x8)0, lo = (s16x8)0;
      if (g < M) {
        hi = *(const s16x8*)&Xb[(size_t)g * K2 + k0 + sq];
        lo = *(const s16x8*)&Xb[(size_t)g * K2 + K + k0 + sq];
      }
      *(s16x8*)&sA[0][sr][sq] = hi;
      *(s16x8*)&sA[1][sr][sq] = lo;
    }
    {
      int g = bn + sr;
      *(s16x8*)&sB[0][sr][sq] = *(const s16x8*)&Wtb[(size_t)g * K2 + k0 + sq];
      *(s16x8*)&sB[1][sr][sq] = *(const s16x8*)&Wtb[(size_t)g * K2 + K + k0 + sq];
    }
    __syncthreads();

    s16x8 aH[2], aL[2], bH[2], bL[2];
#pragma unroll
    for (int mt = 0; mt < 2; mt++) {
      aH[mt] = *(const s16x8*)&sA[0][wr * 32 + mt * 16 + lrow][k8];
      aL[mt] = *(const s16x8*)&sA[1][wr * 32 + mt * 16 + lrow][k8];
    }
#pragma unroll
    for (int nt = 0; nt < 2; nt++) {
      bH[nt] = *(const s16x8*)&sB[0][wc * 32 + nt * 16 + lrow][k8];
      bL[nt] = *(const s16x8*)&sB[1][wc * 32 + nt * 16 + lrow][k8];
    }
#pragma unroll
    for (int mt = 0; mt < 2; mt++)
#pragma unroll
      for (int nt = 0; nt < 2; nt++) {
        acc[mt][nt] = __builtin_amdgcn_mfma_f32_16x16x32_bf16(aH[mt], bH[nt], acc[mt][nt], 0, 0, 0);
        acc[mt][nt] = __builtin_amdgcn_mfma_f32_16x16x32_bf16(aH[mt], bL[nt], acc[mt][nt], 0, 0, 0);
        acc[mt][nt] = __builtin_amdgcn_mfma_f32_16x16x32_bf16(aL[mt], bH[nt], acc[mt][nt], 0, 0, 0);
      }
    __syncthreads();
  }

  int dcol = l & 15, drow4 = (l >> 4) * 4;
#pragma unroll
  for (int mt = 0; mt < 2; mt++)
#pragma unroll
    for (int nt = 0; nt < 2; nt++) {
      int col = bn + wc * 32 + nt * 16 + dcol;
#pragma unroll
      for (int r = 0; r < 4; r++) {
        int row = bm + wr * 32 + mt * 16 + drow4 + r;
        if (row < M) C[(size_t)row * N + col] = acc[mt][nt][r];
      }
    }
}

// ---------- per-node attention scores (H row stride ld, F live cols)
__global__ __launch_bounds__(256) void row_dots(const float* __restrict__ H,
    const float* __restrict__ a_s, const float* __restrict__ a_d,
    float* __restrict__ s_src, float* __restrict__ s_dst, int Nn, int F, int ld) {
  int node = blockIdx.x * 4 + (threadIdx.x >> 6);
  int lane = threadIdx.x & 63;
  if (node >= Nn) return;
  float ss = 0.f, sd = 0.f;
  for (int c = lane; c < F; c += 64) {
    float h = H[(size_t)node * ld + c];
    ss += h * a_s[c];
    sd += h * a_d[c];
  }
#pragma unroll
  for (int off = 32; off > 0; off >>= 1) {
    ss += __shfl_down(ss, off);
    sd += __shfl_down(sd, off);
  }
  if (lane == 0) { s_src[node] = ss; s_dst[node] = sd; }
}

// ---------- CSR build
__global__ __launch_bounds__(256) void deg_hist(const int* __restrict__ dst,
    int* __restrict__ deg, int E) {
  int e = blockIdx.x * 256 + threadIdx.x;
  if (e >= E) return;
  atomicAdd(&deg[dst[e]], 1);
}

__global__ __launch_bounds__(1024) void scan_rowptr(const int* __restrict__ deg,
    int* __restrict__ rowptr, int N) {
  __shared__ int sdata[1024];
  __shared__ int carry;
  int tid = threadIdx.x;
  if (tid == 0) carry = 0;
  __syncthreads();
  for (int base = 0; base < N; base += 1024) {
    int idx = base + tid;
    int v = (idx < N) ? deg[idx] : 0;
    sdata[tid] = v;
    __syncthreads();
    for (int off = 1; off < 1024; off <<= 1) {
      int t = (tid >= off) ? sdata[tid - off] : 0;
      __syncthreads();
      sdata[tid] += t;
      __syncthreads();
    }
    int incl = sdata[tid];
    if (idx < N) rowptr[idx] = carry + incl - v;
    __syncthreads();
    if (tid == 1023) carry += sdata[1023];
    __syncthreads();
  }
  if (tid == 0) rowptr[N] = carry;
}

__global__ __launch_bounds__(256) void csr_place(const int* __restrict__ src,
    const int* __restrict__ dst, const int* __restrict__ rowptr,
    int* __restrict__ cnt, int* __restrict__ csr_src, int E) {
  int e = blockIdx.x * 256 + threadIdx.x;
  if (e >= E) return;
  int d = dst[e];
  int pos = rowptr[d] + atomicAdd(&cnt[d], 1);
  csr_src[pos] = src[e];
}

// ---------- per-node softmax over in-edges -> alpha
__global__ __launch_bounds__(256) void attn_node(const float* __restrict__ ssrc,
    const float* __restrict__ sdst, const int* __restrict__ rowptr,
    const int* __restrict__ csr_src, float* __restrict__ alpha, int N) {
  int node = blockIdx.x * 4 + (threadIdx.x >> 6);
  int lane = threadIdx.x & 63;
  if (node >= N) return;
  int r0 = rowptr[node], r1 = rowptr[node + 1];
  if (r0 == r1) return;
  float sd = sdst[node];
  float m = -1e30f;
  for (int i = r0 + lane; i < r1; i += 64) {
    float v = ssrc[csr_src[i]] + sd;
    v = v > 0.f ? v : v * NEG_ATT;
    alpha[i] = v;
    m = fmaxf(m, v);
  }
#pragma unroll
  for (int off = 32; off > 0; off >>= 1) m = fmaxf(m, __shfl_xor(m, off));
  float s = 0.f;
  for (int i = r0 + lane; i < r1; i += 64) {
    float x = expf(alpha[i] - m);
    alpha[i] = x;
    s += x;
  }
#pragma unroll
  for (int off = 32; off > 0; off >>= 1) s += __shfl_xor(s, off);
  float inv = 1.f / s;
  for (int i = r0 + lane; i < r1; i += 64) alpha[i] *= inv;
}

// ---------- gather aggregation F=256: wave per node, lane owns 4 channels.
// out: bf16 split [node][512] (hi|lo) with bias+leaky fused.
__global__ __launch_bounds__(256) void agg256_v2(const float* __restrict__ H,
    const int* __restrict__ rowptr, const int* __restrict__ csr_src,
    const float* __restrict__ alpha, const float* __restrict__ b,
    short* __restrict__ outb, int N, float slope) {
  int node = blockIdx.x * 4 + (threadIdx.x >> 6);
  int lane = threadIdx.x & 63;
  if (node >= N) return;
  int c4 = lane * 4;
  int r0 = rowptr[node], r1 = rowptr[node + 1];
  float x0 = 0.f, y0 = 0.f, z0 = 0.f, w0 = 0.f;
  float x1 = 0.f, y1 = 0.f, z1 = 0.f, w1 = 0.f;
  int i = r0;
  for (; i + 2 <= r1; i += 2) {
    int s0 = csr_src[i], s1 = csr_src[i + 1];
    float a0 = alpha[i], a1 = alpha[i + 1];
    float4 h0 = *(const float4*)&H[(size_t)s0 * 256 + c4];
    float4 h1 = *(const float4*)&H[(size_t)s1 * 256 + c4];
    x0 += a0 * h0.x; y0 += a0 * h0.y; z0 += a0 * h0.z; w0 += a0 * h0.w;
    x1 += a1 * h1.x; y1 += a1 * h1.y; z1 += a1 * h1.z; w1 += a1 * h1.w;
  }
  if (i < r1) {
    int s0 = csr_src[i];
    float a0 = alpha[i];
    float4 h0 = *(const float4*)&H[(size_t)s0 * 256 + c4];
    x0 += a0 * h0.x; y0 += a0 * h0.y; z0 += a0 * h0.z; w0 += a0 * h0.w;
  }
  float4 bias = *(const float4*)&b[c4];
  float vx = x0 + x1 + bias.x, vy = y0 + y1 + bias.y;
  float vz = z0 + z1 + bias.z, vw = w0 + w1 + bias.w;
  vx = vx > 0.f ? vx : vx * slope;
  vy = vy > 0.f ? vy : vy * slope;
  vz = vz > 0.f ? vz : vz * slope;
  vw = vw > 0.f ? vw : vw * slope;
  short4 hi, lo;
  hi.x = f2bf_rn(vx); lo.x = f2bf_rn(vx - bf2f(hi.x));
  hi.y = f2bf_rn(vy); lo.y = f2bf_rn(vy - bf2f(hi.y));
  hi.z = f2bf_rn(vz); lo.z = f2bf_rn(vz - bf2f(hi.z));
  hi.w = f2bf_rn(vw); lo.w = f2bf_rn(vw - bf2f(hi.w));
  *(short4*)&outb[(size_t)node * 512 + c4] = hi;
  *(short4*)&outb[(size_t)node * 512 + 256 + c4] = lo;
}

// ---------- layer-3 aggregation, first-node-of-graph only, writes d_out directly
__global__ __launch_bounds__(256) void agg16(const float* __restrict__ H,
    const int* __restrict__ rowptr, const int* __restrict__ csr_src,
    const float* __restrict__ alpha, const float* __restrict__ b,
    const int* __restrict__ batch, float* __restrict__ out, int N, int ld) {
  int node = blockIdx.x * 16 + (threadIdx.x >> 4);
  int c = threadIdx.x & 15;
  if (node >= N) return;
  if (node != 0 && batch[node] == batch[node - 1]) return;  // not first of graph
  int r0 = rowptr[node], r1 = rowptr[node + 1];
  float acc = 0.f;
  for (int i = r0; i < r1; i++) acc += alpha[i] * H[(size_t)csr_src[i] * ld + c];
  out[(size_t)batch[node] * 16 + c] = acc + b[c];
}

extern "C" void kernel_launch(void* const* d_in, const int* in_sizes, int n_in,
                              void* d_out, int out_size, void* d_ws, size_t ws_size,
                              hipStream_t stream) {
  const float* x   = (const float*)d_in[0];
  const int* src   = (const int*)d_in[1];
  const int* dst   = (const int*)d_in[2];
  const int* batch = (const int*)d_in[3];
  const float* W1 = (const float*)d_in[4];
  const float* as1 = (const float*)d_in[5];
  const float* ad1 = (const float*)d_in[6];
  const float* b1 = (const float*)d_in[7];
  const float* W2 = (const float*)d_in[8];
  const float* as2 = (const float*)d_in[9];
  const float* ad2 = (const float*)d_in[10];
  const float* b2 = (const float*)d_in[11];
  const float* W3 = (const float*)d_in[12];
  const float* as3 = (const float*)d_in[13];
  const float* ad3 = (const float*)d_in[14];
  const float* b3 = (const float*)d_in[15];

  const int N = in_sizes[3];   // 50000 nodes
  const int E = in_sizes[1];   // 800000 edges

  char* ws = (char*)d_ws;
  size_t off = 0;
  auto alloc = [&](size_t bytes) -> void* {
    void* p = ws + off;
    off = (off + bytes + 255) & ~(size_t)255;
    return p;
  };
  float* A      = (float*)alloc((size_t)N * 256 * 4);  // GEMM out fp32; layer-3 h3 aliases (N*64)
  short* Xb     = (short*)alloc((size_t)N * 512 * 2);  // bf16 split input (layer1: N*256 used)
  float* ssrc   = (float*)alloc((size_t)N * 4);
  float* sdst   = (float*)alloc((size_t)N * 4);
  float* alpha  = (float*)alloc((size_t)E * 4);
  int* deg      = (int*)alloc((size_t)N * 4);
  int* rowptr   = (int*)alloc((size_t)(N + 1) * 4);
  int* cnt      = (int*)alloc((size_t)N * 4);
  int* csr_src  = (int*)alloc((size_t)E * 4);
  short* W1tb   = (short*)alloc((size_t)256 * 256 * 2);
  short* W2tb   = (short*)alloc((size_t)256 * 512 * 2);
  short* W3tb   = (short*)alloc((size_t)64 * 512 * 2);   // padded to 64 rows
  float* h3     = A;                                      // aliases A (N*64 floats)
  (void)ws_size;

  dim3 blk(256);
  int eblocks = (E + 255) / 256;
  int gblocksY = (N + 63) / 64;
  int nb4 = (N + 3) / 4;

  // ---- conversions + CSR build
  conv_w<<<(128 * 256 + 255) / 256, blk, 0, stream>>>(W1, W1tb, 128, 256);
  conv_w<<<(256 * 256 + 255) / 256, blk, 0, stream>>>(W2, W2tb, 256, 256);
  (void)hipMemsetAsync(W3tb, 0, (size_t)64 * 512 * 2, stream);
  conv_w<<<(256 * 16 + 255) / 256, blk, 0, stream>>>(W3, W3tb, 256, 16);
  conv_x<<<(int)(((long long)N * 32 + 255) / 256), blk, 0, stream>>>(x, Xb, N, 128);
  (void)hipMemsetAsync(deg, 0, (size_t)N * 4, stream);
  deg_hist<<<eblocks, blk, 0, stream>>>(dst, deg, E);
  scan_rowptr<<<1, 1024, 0, stream>>>(deg, rowptr, N);
  (void)hipMemsetAsync(cnt, 0, (size_t)N * 4, stream);
  csr_place<<<eblocks, blk, 0, stream>>>(src, dst, rowptr, cnt, csr_src, E);

  // ---- layer 1: A = x @ W1  (K=128), attention, agg -> Xb (bf16 split)
  gemm_bf16split<<<dim3(4, gblocksY), blk, 0, stream>>>(Xb, W1tb, A, N, 256, 128);
  row_dots<<<nb4, blk, 0, stream>>>(A, as1, ad1, ssrc, sdst, N, 256, 256);
  attn_node<<<nb4, blk, 0, stream>>>(ssrc, sdst, rowptr, csr_src, alpha, N);
  agg256_v2<<<nb4, blk, 0, stream>>>(A, rowptr, csr_src, alpha, b1, Xb, N, NEG_ACT);

  // ---- layer 2: A = h1 @ W2  (K=256), attention, agg -> Xb (bf16 split)
  gemm_bf16split<<<dim3(4, gblocksY), blk, 0, stream>>>(Xb, W2tb, A, N, 256, 256);
  row_dots<<<nb4, blk, 0, stream>>>(A, as2, ad2, ssrc, sdst, N, 256, 256);
  attn_node<<<nb4, blk, 0, stream>>>(ssrc, sdst, rowptr, csr_src, alpha, N);
  agg256_v2<<<nb4, blk, 0, stream>>>(A, rowptr, csr_src, alpha, b2, Xb, N, NEG_ACT);

  // ---- layer 3: h3 = h2 @ W3 (padded N=64, K=256), attention, agg -> d_out
  gemm_bf16split<<<dim3(1, gblocksY), blk, 0, stream>>>(Xb, W3tb, h3, N, 64, 256);
  row_dots<<<nb4, blk, 0, stream>>>(h3, as3, ad3, ssrc, sdst, N, 16, 64);
  attn_node<<<nb4, blk, 0, stream>>>(ssrc, sdst, rowptr, csr_src, alpha, N);
  agg16<<<(N + 15) / 16, blk, 0, stream>>>(h3, rowptr, csr_src, alpha, b3, batch,
                                           (float*)d_out, N, 64);
}

// Round 14
// 471.474 us; speedup vs baseline: 12.9867x; 1.2907x over previous
//
#include <hip/hip_runtime.h>

#define NEG_ATT 0.2f
#define NEG_ACT 0.01f

typedef short s16x8 __attribute__((ext_vector_type(8)));
typedef float f32x4 __attribute__((ext_vector_type(4)));

__device__ __forceinline__ short f2bf_rn(float f) {
  unsigned u = __float_as_uint(f);
  unsigned r = (u + 0x7FFFu + ((u >> 16) & 1u)) >> 16;
  return (short)r;
}
__device__ __forceinline__ float bf2f(short h) {
  return __uint_as_float(((unsigned)(unsigned short)h) << 16);
}

// ---------- convert X fp32 [M][K] -> Xb bf16 [M][2K] (hi cols 0..K-1, lo K..2K-1)
__global__ __launch_bounds__(256) void conv_x(const float* __restrict__ X,
    short* __restrict__ Xb, int M, int K) {
  long long gid = (long long)blockIdx.x * 256 + threadIdx.x;
  long long tot = (long long)M * (K / 4);
  if (gid >= tot) return;
  int row = (int)(gid / (K / 4));
  int c4 = ((int)(gid % (K / 4))) * 4;
  float4 v = *(const float4*)&X[(size_t)row * K + c4];
  short4 hi, lo;
  hi.x = f2bf_rn(v.x); lo.x = f2bf_rn(v.x - bf2f(hi.x));
  hi.y = f2bf_rn(v.y); lo.y = f2bf_rn(v.y - bf2f(hi.y));
  hi.z = f2bf_rn(v.z); lo.z = f2bf_rn(v.z - bf2f(hi.z));
  hi.w = f2bf_rn(v.w); lo.w = f2bf_rn(v.w - bf2f(hi.w));
  *(short4*)&Xb[(size_t)row * 2 * K + c4] = hi;
  *(short4*)&Xb[(size_t)row * 2 * K + K + c4] = lo;
}

// ---------- convert+transpose W fp32 [K][N] -> Wtb bf16 [N][2K]
__global__ __launch_bounds__(256) void conv_w(const float* __restrict__ W,
    short* __restrict__ Wtb, int K, int N) {
  int gid = blockIdx.x * 256 + threadIdx.x;
  if (gid >= K * N) return;
  int k = gid / N, n = gid % N;
  float v = W[(size_t)k * N + n];
  short hi = f2bf_rn(v);
  short lo = f2bf_rn(v - bf2f(hi));
  Wtb[(size_t)n * 2 * K + k] = hi;
  Wtb[(size_t)n * 2 * K + K + k] = lo;
}

// ---------- split-bf16 MFMA GEMM: Cb[M][ldc] (bf16) = X[M,K] @ W[K,N], ~fp32 internal
__global__ __launch_bounds__(256) void gemm_bf16split(const short* __restrict__ Xb,
    const short* __restrict__ Wtb, short* __restrict__ Cb, int M, int N, int K, int ldc) {
  __shared__ short sA[2][64][40];
  __shared__ short sB[2][64][40];
  const int K2 = 2 * K;
  int tid = threadIdx.x;
  int w = tid >> 6, l = tid & 63;
  int wr = w >> 1, wc = w & 1;
  int bm = blockIdx.y * 64, bn = blockIdx.x * 64;
  int sr = tid >> 2, sq = (tid & 3) * 8;

  f32x4 acc[2][2];
#pragma unroll
  for (int i = 0; i < 2; i++)
#pragma unroll
    for (int j = 0; j < 2; j++) acc[i][j] = (f32x4)0.f;

  int lrow = l & 15, k8 = (l >> 4) * 8;

  for (int k0 = 0; k0 < K; k0 += 32) {
    {
      int g = bm + sr;
      s16x8 hi = (s16x8)0, lo = (s16x8)0;
      if (g < M) {
        hi = *(const s16x8*)&Xb[(size_t)g * K2 + k0 + sq];
        lo = *(const s16x8*)&Xb[(size_t)g * K2 + K + k0 + sq];
      }
      *(s16x8*)&sA[0][sr][sq] = hi;
      *(s16x8*)&sA[1][sr][sq] = lo;
    }
    {
      int g = bn + sr;
      *(s16x8*)&sB[0][sr][sq] = *(const s16x8*)&Wtb[(size_t)g * K2 + k0 + sq];
      *(s16x8*)&sB[1][sr][sq] = *(const s16x8*)&Wtb[(size_t)g * K2 + K + k0 + sq];
    }
    __syncthreads();

    s16x8 aH[2], aL[2], bH[2], bL[2];
#pragma unroll
    for (int mt = 0; mt < 2; mt++) {
      aH[mt] = *(const s16x8*)&sA[0][wr * 32 + mt * 16 + lrow][k8];
      aL[mt] = *(const s16x8*)&sA[1][wr * 32 + mt * 16 + lrow][k8];
    }
#pragma unroll
    for (int nt = 0; nt < 2; nt++) {
      bH[nt] = *(const s16x8*)&sB[0][wc * 32 + nt * 16 + lrow][k8];
      bL[nt] = *(const s16x8*)&sB[1][wc * 32 + nt * 16 + lrow][k8];
    }
#pragma unroll
    for (int mt = 0; mt < 2; mt++)
#pragma unroll
      for (int nt = 0; nt < 2; nt++) {
        acc[mt][nt] = __builtin_amdgcn_mfma_f32_16x16x32_bf16(aH[mt], bH[nt], acc[mt][nt], 0, 0, 0);
        acc[mt][nt] = __builtin_amdgcn_mfma_f32_16x16x32_bf16(aH[mt], bL[nt], acc[mt][nt], 0, 0, 0);
        acc[mt][nt] = __builtin_amdgcn_mfma_f32_16x16x32_bf16(aL[mt], bH[nt], acc[mt][nt], 0, 0, 0);
      }
    __syncthreads();
  }

  int dcol = l & 15, drow4 = (l >> 4) * 4;
#pragma unroll
  for (int mt = 0; mt < 2; mt++)
#pragma unroll
    for (int nt = 0; nt < 2; nt++) {
      int col = bn + wc * 32 + nt * 16 + dcol;
      if (col < N) {
#pragma unroll
        for (int r = 0; r < 4; r++) {
          int row = bm + wr * 32 + mt * 16 + drow4 + r;
          if (row < M) Cb[(size_t)row * ldc + col] = f2bf_rn(acc[mt][nt][r]);
        }
      }
    }
}

// ---------- per-node attention scores from bf16 H (row stride ld, F live cols)
__global__ __launch_bounds__(256) void row_dots(const short* __restrict__ Hb,
    const float* __restrict__ a_s, const float* __restrict__ a_d,
    float* __restrict__ s_src, float* __restrict__ s_dst, int Nn, int F, int ld) {
  int node = blockIdx.x * 4 + (threadIdx.x >> 6);
  int lane = threadIdx.x & 63;
  if (node >= Nn) return;
  float ss = 0.f, sd = 0.f;
  for (int c = lane; c < F; c += 64) {
    float h = bf2f(Hb[(size_t)node * ld + c]);
    ss += h * a_s[c];
    sd += h * a_d[c];
  }
#pragma unroll
  for (int off = 32; off > 0; off >>= 1) {
    ss += __shfl_down(ss, off);
    sd += __shfl_down(sd, off);
  }
  if (lane == 0) { s_src[node] = ss; s_dst[node] = sd; }
}

// ---------- CSR build
__global__ __launch_bounds__(256) void deg_hist(const int* __restrict__ dst,
    int* __restrict__ deg, int E) {
  int e = blockIdx.x * 256 + threadIdx.x;
  if (e >= E) return;
  atomicAdd(&deg[dst[e]], 1);
}

__global__ __launch_bounds__(1024) void scan_rowptr(const int* __restrict__ deg,
    int* __restrict__ rowptr, int N) {
  __shared__ int sdata[1024];
  __shared__ int carry;
  int tid = threadIdx.x;
  if (tid == 0) carry = 0;
  __syncthreads();
  for (int base = 0; base < N; base += 1024) {
    int idx = base + tid;
    int v = (idx < N) ? deg[idx] : 0;
    sdata[tid] = v;
    __syncthreads();
    for (int off = 1; off < 1024; off <<= 1) {
      int t = (tid >= off) ? sdata[tid - off] : 0;
      __syncthreads();
      sdata[tid] += t;
      __syncthreads();
    }
    int incl = sdata[tid];
    if (idx < N) rowptr[idx] = carry + incl - v;
    __syncthreads();
    if (tid == 1023) carry += sdata[1023];
    __syncthreads();
  }
  if (tid == 0) rowptr[N] = carry;
}

__global__ __launch_bounds__(256) void csr_place(const int* __restrict__ src,
    const int* __restrict__ dst, const int* __restrict__ rowptr,
    int* __restrict__ cnt, int* __restrict__ csr_src, int E) {
  int e = blockIdx.x * 256 + threadIdx.x;
  if (e >= E) return;
  int d = dst[e];
  int pos = rowptr[d] + atomicAdd(&cnt[d], 1);
  csr_src[pos] = src[e];
}

// ---------- fused softmax + aggregation, F=256: wave per node.
// pass1/2: edge-parallel softmax (alpha scratch); pass3: channel-parallel gather of bf16 H.
// out: bf16 split [node][512] (hi|lo), bias+leaky fused.
__global__ __launch_bounds__(256) void attn_agg256(const short* __restrict__ Hb,
    const float* __restrict__ ssrc, const float* __restrict__ sdst,
    const int* __restrict__ rowptr, const int* __restrict__ csr_src,
    float* __restrict__ alpha, const float* __restrict__ b,
    short* __restrict__ outb, int N, float slope) {
  int node = blockIdx.x * 4 + (threadIdx.x >> 6);
  int lane = threadIdx.x & 63;
  if (node >= N) return;
  int r0 = rowptr[node], r1 = rowptr[node + 1];
  float sd = sdst[node];
  // pass 1: scores -> alpha, running max
  float m = -1e30f;
  for (int i = r0 + lane; i < r1; i += 64) {
    float v = ssrc[csr_src[i]] + sd;
    v = v > 0.f ? v : v * NEG_ATT;
    alpha[i] = v;
    m = fmaxf(m, v);
  }
#pragma unroll
  for (int off = 32; off > 0; off >>= 1) m = fmaxf(m, __shfl_xor(m, off));
  // pass 2: exp -> alpha, sum
  float s = 0.f;
  for (int i = r0 + lane; i < r1; i += 64) {
    float x = expf(alpha[i] - m);
    alpha[i] = x;
    s += x;
  }
#pragma unroll
  for (int off = 32; off > 0; off >>= 1) s += __shfl_xor(s, off);
  float inv = 1.f / s;
  // pass 3: aggregate, lane owns 4 channels
  int c4 = lane * 4;
  float x0 = 0.f, y0 = 0.f, z0 = 0.f, w0 = 0.f;
  float x1 = 0.f, y1 = 0.f, z1 = 0.f, w1 = 0.f;
  int i = r0;
  for (; i + 2 <= r1; i += 2) {
    int s0 = csr_src[i], s1 = csr_src[i + 1];
    float a0 = alpha[i], a1 = alpha[i + 1];
    short4 h0 = *(const short4*)&Hb[(size_t)s0 * 256 + c4];
    short4 h1 = *(const short4*)&Hb[(size_t)s1 * 256 + c4];
    x0 += a0 * bf2f(h0.x); y0 += a0 * bf2f(h0.y);
    z0 += a0 * bf2f(h0.z); w0 += a0 * bf2f(h0.w);
    x1 += a1 * bf2f(h1.x); y1 += a1 * bf2f(h1.y);
    z1 += a1 * bf2f(h1.z); w1 += a1 * bf2f(h1.w);
  }
  if (i < r1) {
    int s0 = csr_src[i];
    float a0 = alpha[i];
    short4 h0 = *(const short4*)&Hb[(size_t)s0 * 256 + c4];
    x0 += a0 * bf2f(h0.x); y0 += a0 * bf2f(h0.y);
    z0 += a0 * bf2f(h0.z); w0 += a0 * bf2f(h0.w);
  }
  float4 bias = *(const float4*)&b[c4];
  float vx = (x0 + x1) * inv + bias.x, vy = (y0 + y1) * inv + bias.y;
  float vz = (z0 + z1) * inv + bias.z, vw = (w0 + w1) * inv + bias.w;
  if (r0 == r1) { vx = bias.x; vy = bias.y; vz = bias.z; vw = bias.w; }
  vx = vx > 0.f ? vx : vx * slope;
  vy = vy > 0.f ? vy : vy * slope;
  vz = vz > 0.f ? vz : vz * slope;
  vw = vw > 0.f ? vw : vw * slope;
  short4 hi, lo;
  hi.x = f2bf_rn(vx); lo.x = f2bf_rn(vx - bf2f(hi.x));
  hi.y = f2bf_rn(vy); lo.y = f2bf_rn(vy - bf2f(hi.y));
  hi.z = f2bf_rn(vz); lo.z = f2bf_rn(vz - bf2f(hi.z));
  hi.w = f2bf_rn(vw); lo.w = f2bf_rn(vw - bf2f(hi.w));
  *(short4*)&outb[(size_t)node * 512 + c4] = hi;
  *(short4*)&outb[(size_t)node * 512 + 256 + c4] = lo;
}

// ---------- fused softmax + aggregation, layer 3, first-of-graph nodes only.
// wave per node; pass3: lane = (edge slot, channel); writes d_out fp32.
__global__ __launch_bounds__(256) void attn_agg16(const short* __restrict__ Hb,
    const float* __restrict__ ssrc, const float* __restrict__ sdst,
    const int* __restrict__ rowptr, const int* __restrict__ csr_src,
    float* __restrict__ alpha, const float* __restrict__ b,
    const int* __restrict__ batch, float* __restrict__ out, int N, int ld) {
  int node = blockIdx.x * 4 + (threadIdx.x >> 6);
  int lane = threadIdx.x & 63;
  if (node >= N) return;
  if (node != 0 && batch[node] == batch[node - 1]) return;  // not first of graph
  int r0 = rowptr[node], r1 = rowptr[node + 1];
  float sd = sdst[node];
  float m = -1e30f;
  for (int i = r0 + lane; i < r1; i += 64) {
    float v = ssrc[csr_src[i]] + sd;
    v = v > 0.f ? v : v * NEG_ATT;
    alpha[i] = v;
    m = fmaxf(m, v);
  }
#pragma unroll
  for (int off = 32; off > 0; off >>= 1) m = fmaxf(m, __shfl_xor(m, off));
  float s = 0.f;
  for (int i = r0 + lane; i < r1; i += 64) {
    float x = expf(alpha[i] - m);
    alpha[i] = x;
    s += x;
  }
#pragma unroll
  for (int off = 32; off > 0; off >>= 1) s += __shfl_xor(s, off);
  float inv = 1.f / s;
  // pass 3: c = lane&15 channel, eg = lane>>4 edge slot (4 slots)
  int c = lane & 15, eg = lane >> 4;
  float acc = 0.f;
  for (int i = r0 + eg; i < r1; i += 4)
    acc += alpha[i] * bf2f(Hb[(size_t)csr_src[i] * ld + c]);
#pragma unroll
  for (int off = 16; off < 64; off <<= 1) acc += __shfl_xor(acc, off);
  if (eg == 0) out[(size_t)batch[node] * 16 + c] = acc * inv + b[c];
}

extern "C" void kernel_launch(void* const* d_in, const int* in_sizes, int n_in,
                              void* d_out, int out_size, void* d_ws, size_t ws_size,
                              hipStream_t stream) {
  const float* x   = (const float*)d_in[0];
  const int* src   = (const int*)d_in[1];
  const int* dst   = (const int*)d_in[2];
  const int* batch = (const int*)d_in[3];
  const float* W1 = (const float*)d_in[4];
  const float* as1 = (const float*)d_in[5];
  const float* ad1 = (const float*)d_in[6];
  const float* b1 = (const float*)d_in[7];
  const float* W2 = (const float*)d_in[8];
  const float* as2 = (const float*)d_in[9];
  const float* ad2 = (const float*)d_in[10];
  const float* b2 = (const float*)d_in[11];
  const float* W3 = (const float*)d_in[12];
  const float* as3 = (const float*)d_in[13];
  const float* ad3 = (const float*)d_in[14];
  const float* b3 = (const float*)d_in[15];

  const int N = in_sizes[3];   // 50000 nodes
  const int E = in_sizes[1];   // 800000 edges

  char* ws = (char*)d_ws;
  size_t off = 0;
  auto alloc = [&](size_t bytes) -> void* {
    void* p = ws + off;
    off = (off + bytes + 255) & ~(size_t)255;
    return p;
  };
  short* Hb     = (short*)alloc((size_t)N * 256 * 2);  // bf16 h (layer3 uses ld=64 prefix)
  short* Xb     = (short*)alloc((size_t)N * 512 * 2);  // bf16 split GEMM input
  float* ssrc   = (float*)alloc((size_t)N * 4);
  float* sdst   = (float*)alloc((size_t)N * 4);
  float* alpha  = (float*)alloc((size_t)E * 4);
  int* deg      = (int*)alloc((size_t)N * 4);
  int* rowptr   = (int*)alloc((size_t)(N + 1) * 4);
  int* cnt      = (int*)alloc((size_t)N * 4);
  int* csr_src  = (int*)alloc((size_t)E * 4);
  short* W1tb   = (short*)alloc((size_t)256 * 256 * 2);
  short* W2tb   = (short*)alloc((size_t)256 * 512 * 2);
  short* W3tb   = (short*)alloc((size_t)64 * 512 * 2);   // padded to 64 rows
  (void)ws_size;

  dim3 blk(256);
  int eblocks = (E + 255) / 256;
  int gblocksY = (N + 63) / 64;
  int nb4 = (N + 3) / 4;

  // ---- conversions + CSR build
  conv_w<<<(128 * 256 + 255) / 256, blk, 0, stream>>>(W1, W1tb, 128, 256);
  conv_w<<<(256 * 256 + 255) / 256, blk, 0, stream>>>(W2, W2tb, 256, 256);
  (void)hipMemsetAsync(W3tb, 0, (size_t)64 * 512 * 2, stream);
  conv_w<<<(256 * 16 + 255) / 256, blk, 0, stream>>>(W3, W3tb, 256, 16);
  conv_x<<<(int)(((long long)N * 32 + 255) / 256), blk, 0, stream>>>(x, Xb, N, 128);
  (void)hipMemsetAsync(deg, 0, (size_t)N * 4, stream);
  deg_hist<<<eblocks, blk, 0, stream>>>(dst, deg, E);
  scan_rowptr<<<1, 1024, 0, stream>>>(deg, rowptr, N);
  (void)hipMemsetAsync(cnt, 0, (size_t)N * 4, stream);
  csr_place<<<eblocks, blk, 0, stream>>>(src, dst, rowptr, cnt, csr_src, E);

  // ---- layer 1: Hb = x @ W1 (bf16), scores, fused attn+agg -> Xb (bf16 split)
  gemm_bf16split<<<dim3(4, gblocksY), blk, 0, stream>>>(Xb, W1tb, Hb, N, 256, 128, 256);
  row_dots<<<nb4, blk, 0, stream>>>(Hb, as1, ad1, ssrc, sdst, N, 256, 256);
  attn_agg256<<<nb4, blk, 0, stream>>>(Hb, ssrc, sdst, rowptr, csr_src, alpha, b1, Xb, N, NEG_ACT);

  // ---- layer 2
  gemm_bf16split<<<dim3(4, gblocksY), blk, 0, stream>>>(Xb, W2tb, Hb, N, 256, 256, 256);
  row_dots<<<nb4, blk, 0, stream>>>(Hb, as2, ad2, ssrc, sdst, N, 256, 256);
  attn_agg256<<<nb4, blk, 0, stream>>>(Hb, ssrc, sdst, rowptr, csr_src, alpha, b2, Xb, N, NEG_ACT);

  // ---- layer 3: Hb[:, :64] = h2 @ W3 (padded N=64), scores, fused attn+agg (first nodes) -> d_out
  gemm_bf16split<<<dim3(1, gblocksY), blk, 0, stream>>>(Xb, W3tb, Hb, N, 64, 256, 64);
  row_dots<<<nb4, blk, 0, stream>>>(Hb, as3, ad3, ssrc, sdst, N, 16, 64);
  attn_agg16<<<nb4, blk, 0, stream>>>(Hb, ssrc, sdst, rowptr, csr_src, alpha, b3, batch,
                                      (float*)d_out, N, 64);
}

// Round 22
// 385.950 us; speedup vs baseline: 15.8645x; 1.2216x over previous
//
#include <hip/hip_runtime.h>

#define NEG_ATT 0.2f
#define NEG_ACT 0.01f

typedef short s16x8 __attribute__((ext_vector_type(8)));
typedef float f32x4 __attribute__((ext_vector_type(4)));

__device__ __forceinline__ short f2bf_rn(float f) {
  unsigned u = __float_as_uint(f);
  unsigned r = (u + 0x7FFFu + ((u >> 16) & 1u)) >> 16;
  return (short)r;
}
__device__ __forceinline__ float bf2f(short h) {
  return __uint_as_float(((unsigned)(unsigned short)h) << 16);
}

// ---------- convert X fp32 [M][K] -> Xb bf16 [M][2K] (hi cols 0..K-1, lo K..2K-1)
__global__ __launch_bounds__(256) void conv_x(const float* __restrict__ X,
    short* __restrict__ Xb, int M, int K) {
  long long gid = (long long)blockIdx.x * 256 + threadIdx.x;
  long long tot = (long long)M * (K / 4);
  if (gid >= tot) return;
  int row = (int)(gid / (K / 4));
  int c4 = ((int)(gid % (K / 4))) * 4;
  float4 v = *(const float4*)&X[(size_t)row * K + c4];
  short4 hi, lo;
  hi.x = f2bf_rn(v.x); lo.x = f2bf_rn(v.x - bf2f(hi.x));
  hi.y = f2bf_rn(v.y); lo.y = f2bf_rn(v.y - bf2f(hi.y));
  hi.z = f2bf_rn(v.z); lo.z = f2bf_rn(v.z - bf2f(hi.z));
  hi.w = f2bf_rn(v.w); lo.w = f2bf_rn(v.w - bf2f(hi.w));
  *(short4*)&Xb[(size_t)row * 2 * K + c4] = hi;
  *(short4*)&Xb[(size_t)row * 2 * K + K + c4] = lo;
}

// ---------- convert+transpose W fp32 [K][N] -> Wtb bf16 [N][2K]
__global__ __launch_bounds__(256) void conv_w(const float* __restrict__ W,
    short* __restrict__ Wtb, int K, int N) {
  int gid = blockIdx.x * 256 + threadIdx.x;
  if (gid >= K * N) return;
  int k = gid / N, n = gid % N;
  float v = W[(size_t)k * N + n];
  short hi = f2bf_rn(v);
  short lo = f2bf_rn(v - bf2f(hi));
  Wtb[(size_t)n * 2 * K + k] = hi;
  Wtb[(size_t)n * 2 * K + K + k] = lo;
}

// ---------- split-bf16 MFMA GEMM: Cb[M][ldc] (bf16) = X[M,K] @ W[K,N], ~fp32 internal
__global__ __launch_bounds__(256) void gemm_bf16split(const short* __restrict__ Xb,
    const short* __restrict__ Wtb, short* __restrict__ Cb, int M, int N, int K, int ldc) {
  __shared__ short sA[2][64][40];
  __shared__ short sB[2][64][40];
  const int K2 = 2 * K;
  int tid = threadIdx.x;
  int w = tid >> 6, l = tid & 63;
  int wr = w >> 1, wc = w & 1;
  int bm = blockIdx.y * 64, bn = blockIdx.x * 64;
  int sr = tid >> 2, sq = (tid & 3) * 8;

  f32x4 acc[2][2];
#pragma unroll
  for (int i = 0; i < 2; i++)
#pragma unroll
    for (int j = 0; j < 2; j++) acc[i][j] = (f32x4)0.f;

  int lrow = l & 15, k8 = (l >> 4) * 8;

  for (int k0 = 0; k0 < K; k0 += 32) {
    {
      int g = bm + sr;
      s16x8 hi = (s16x8)0, lo = (s16x8)0;
      if (g < M) {
        hi = *(const s16x8*)&Xb[(size_t)g * K2 + k0 + sq];
        lo = *(const s16x8*)&Xb[(size_t)g * K2 + K + k0 + sq];
      }
      *(s16x8*)&sA[0][sr][sq] = hi;
      *(s16x8*)&sA[1][sr][sq] = lo;
    }
    {
      int g = bn + sr;
      *(s16x8*)&sB[0][sr][sq] = *(const s16x8*)&Wtb[(size_t)g * K2 + k0 + sq];
      *(s16x8*)&sB[1][sr][sq] = *(const s16x8*)&Wtb[(size_t)g * K2 + K + k0 + sq];
    }
    __syncthreads();

    s16x8 aH[2], aL[2], bH[2], bL[2];
#pragma unroll
    for (int mt = 0; mt < 2; mt++) {
      aH[mt] = *(const s16x8*)&sA[0][wr * 32 + mt * 16 + lrow][k8];
      aL[mt] = *(const s16x8*)&sA[1][wr * 32 + mt * 16 + lrow][k8];
    }
#pragma unroll
    for (int nt = 0; nt < 2; nt++) {
      bH[nt] = *(const s16x8*)&sB[0][wc * 32 + nt * 16 + lrow][k8];
      bL[nt] = *(const s16x8*)&sB[1][wc * 32 + nt * 16 + lrow][k8];
    }
#pragma unroll
    for (int mt = 0; mt < 2; mt++)
#pragma unroll
      for (int nt = 0; nt < 2; nt++) {
        acc[mt][nt] = __builtin_amdgcn_mfma_f32_16x16x32_bf16(aH[mt], bH[nt], acc[mt][nt], 0, 0, 0);
        acc[mt][nt] = __builtin_amdgcn_mfma_f32_16x16x32_bf16(aH[mt], bL[nt], acc[mt][nt], 0, 0, 0);
        acc[mt][nt] = __builtin_amdgcn_mfma_f32_16x16x32_bf16(aL[mt], bH[nt], acc[mt][nt], 0, 0, 0);
      }
    __syncthreads();
  }

  int dcol = l & 15, drow4 = (l >> 4) * 4;
#pragma unroll
  for (int mt = 0; mt < 2; mt++)
#pragma unroll
    for (int nt = 0; nt < 2; nt++) {
      int col = bn + wc * 32 + nt * 16 + dcol;
      if (col < N) {
#pragma unroll
        for (int r = 0; r < 4; r++) {
          int row = bm + wr * 32 + mt * 16 + drow4 + r;
          if (row < M) Cb[(size_t)row * ldc + col] = f2bf_rn(acc[mt][nt][r]);
        }
      }
    }
}

// ---------- per-node attention scores from bf16 H (row stride ld, F live cols)
__global__ __launch_bounds__(256) void row_dots(const short* __restrict__ Hb,
    const float* __restrict__ a_s, const float* __restrict__ a_d,
    float* __restrict__ s_src, float* __restrict__ s_dst, int Nn, int F, int ld) {
  int node = blockIdx.x * 4 + (threadIdx.x >> 6);
  int lane = threadIdx.x & 63;
  if (node >= Nn) return;
  float ss = 0.f, sd = 0.f;
  for (int c = lane; c < F; c += 64) {
    float h = bf2f(Hb[(size_t)node * ld + c]);
    ss += h * a_s[c];
    sd += h * a_d[c];
  }
#pragma unroll
  for (int off = 32; off > 0; off >>= 1) {
    ss += __shfl_down(ss, off);
    sd += __shfl_down(sd, off);
  }
  if (lane == 0) { s_src[node] = ss; s_dst[node] = sd; }
}

// ---------- CSR build
__global__ __launch_bounds__(256) void deg_hist(const int* __restrict__ dst,
    int* __restrict__ deg, int E) {
  int e = blockIdx.x * 256 + threadIdx.x;
  if (e >= E) return;
  atomicAdd(&deg[dst[e]], 1);
}

// hierarchical scan: A) per-block sums
__global__ __launch_bounds__(256) void scan_partials(const int* __restrict__ deg,
    int* __restrict__ bsum, int N) {
  __shared__ int sdata[256];
  int i = blockIdx.x * 256 + threadIdx.x;
  sdata[threadIdx.x] = (i < N) ? deg[i] : 0;
  __syncthreads();
  for (int off = 128; off > 0; off >>= 1) {
    if (threadIdx.x < off) sdata[threadIdx.x] += sdata[threadIdx.x + off];
    __syncthreads();
  }
  if (threadIdx.x == 0) bsum[blockIdx.x] = sdata[0];
}

// B) exclusive scan of block sums (nb <= 256*k via carry loop)
__global__ __launch_bounds__(256) void scan_offsets(int* __restrict__ bsum, int nb) {
  __shared__ int sdata[256];
  __shared__ int carry;
  int tid = threadIdx.x;
  if (tid == 0) carry = 0;
  __syncthreads();
  for (int base = 0; base < nb; base += 256) {
    int idx = base + tid;
    int v = (idx < nb) ? bsum[idx] : 0;
    sdata[tid] = v;
    __syncthreads();
    for (int off = 1; off < 256; off <<= 1) {
      int t = (tid >= off) ? sdata[tid - off] : 0;
      __syncthreads();
      sdata[tid] += t;
      __syncthreads();
    }
    if (idx < nb) bsum[idx] = carry + sdata[tid] - v;
    __syncthreads();
    if (tid == 255) carry += sdata[255];
    __syncthreads();
  }
}

// C) per-block exclusive scan + block offset -> rowptr; rowptr[N]=E
__global__ __launch_bounds__(256) void scan_final(const int* __restrict__ deg,
    const int* __restrict__ bsum, int* __restrict__ rowptr, int N, int E) {
  __shared__ int sdata[256];
  int i = blockIdx.x * 256 + threadIdx.x;
  int tid = threadIdx.x;
  int v = (i < N) ? deg[i] : 0;
  sdata[tid] = v;
  __syncthreads();
  for (int off = 1; off < 256; off <<= 1) {
    int t = (tid >= off) ? sdata[tid - off] : 0;
    __syncthreads();
    sdata[tid] += t;
    __syncthreads();
  }
  if (i < N) rowptr[i] = bsum[blockIdx.x] + sdata[tid] - v;
  if (blockIdx.x == 0 && tid == 0) rowptr[N] = E;
}

__global__ __launch_bounds__(256) void csr_place(const int* __restrict__ src,
    const int* __restrict__ dst, const int* __restrict__ rowptr,
    int* __restrict__ cnt, int* __restrict__ csr_src, int E) {
  int e = blockIdx.x * 256 + threadIdx.x;
  if (e >= E) return;
  int d = dst[e];
  int pos = rowptr[d] + atomicAdd(&cnt[d], 1);
  csr_src[pos] = src[e];
}

// ---------- fused softmax (no-max, single pass) + aggregation, F=256: wave per node.
__global__ __launch_bounds__(256) void attn_agg256(const short* __restrict__ Hb,
    const float* __restrict__ ssrc, const float* __restrict__ sdst,
    const int* __restrict__ rowptr, const int* __restrict__ csr_src,
    float* __restrict__ alpha, const float* __restrict__ b,
    short* __restrict__ outb, int N, float slope) {
  int node = blockIdx.x * 4 + (threadIdx.x >> 6);
  int lane = threadIdx.x & 63;
  if (node >= N) return;
  int r0 = rowptr[node], r1 = rowptr[node + 1];
  float sd = sdst[node];
  // pass 1: exp(score) -> alpha, running sum (scores |v| <~ 12, exp safe)
  float s = 0.f;
  for (int i = r0 + lane; i < r1; i += 64) {
    float v = ssrc[csr_src[i]] + sd;
    v = v > 0.f ? v : v * NEG_ATT;
    float x = expf(v);
    alpha[i] = x;
    s += x;
  }
#pragma unroll
  for (int off = 32; off > 0; off >>= 1) s += __shfl_xor(s, off);
  float inv = 1.f / s;
  // pass 2: aggregate, lane owns 4 channels
  int c4 = lane * 4;
  float x0 = 0.f, y0 = 0.f, z0 = 0.f, w0 = 0.f;
  float x1 = 0.f, y1 = 0.f, z1 = 0.f, w1 = 0.f;
  int i = r0;
  for (; i + 2 <= r1; i += 2) {
    int s0 = csr_src[i], s1 = csr_src[i + 1];
    float a0 = alpha[i], a1 = alpha[i + 1];
    short4 h0 = *(const short4*)&Hb[(size_t)s0 * 256 + c4];
    short4 h1 = *(const short4*)&Hb[(size_t)s1 * 256 + c4];
    x0 += a0 * bf2f(h0.x); y0 += a0 * bf2f(h0.y);
    z0 += a0 * bf2f(h0.z); w0 += a0 * bf2f(h0.w);
    x1 += a1 * bf2f(h1.x); y1 += a1 * bf2f(h1.y);
    z1 += a1 * bf2f(h1.z); w1 += a1 * bf2f(h1.w);
  }
  if (i < r1) {
    int s0 = csr_src[i];
    float a0 = alpha[i];
    short4 h0 = *(const short4*)&Hb[(size_t)s0 * 256 + c4];
    x0 += a0 * bf2f(h0.x); y0 += a0 * bf2f(h0.y);
    z0 += a0 * bf2f(h0.z); w0 += a0 * bf2f(h0.w);
  }
  float4 bias = *(const float4*)&b[c4];
  float vx = (x0 + x1) * inv + bias.x, vy = (y0 + y1) * inv + bias.y;
  float vz = (z0 + z1) * inv + bias.z, vw = (w0 + w1) * inv + bias.w;
  if (r0 == r1) { vx = bias.x; vy = bias.y; vz = bias.z; vw = bias.w; }
  vx = vx > 0.f ? vx : vx * slope;
  vy = vy > 0.f ? vy : vy * slope;
  vz = vz > 0.f ? vz : vz * slope;
  vw = vw > 0.f ? vw : vw * slope;
  short4 hi, lo;
  hi.x = f2bf_rn(vx); lo.x = f2bf_rn(vx - bf2f(hi.x));
  hi.y = f2bf_rn(vy); lo.y = f2bf_rn(vy - bf2f(hi.y));
  hi.z = f2bf_rn(vz); lo.z = f2bf_rn(vz - bf2f(hi.z));
  hi.w = f2bf_rn(vw); lo.w = f2bf_rn(vw - bf2f(hi.w));
  *(short4*)&outb[(size_t)node * 512 + c4] = hi;
  *(short4*)&outb[(size_t)node * 512 + 256 + c4] = lo;
}

// ---------- fused softmax (no-max) + aggregation, layer 3, first-of-graph only
__global__ __launch_bounds__(256) void attn_agg16(const short* __restrict__ Hb,
    const float* __restrict__ ssrc, const float* __restrict__ sdst,
    const int* __restrict__ rowptr, const int* __restrict__ csr_src,
    float* __restrict__ alpha, const float* __restrict__ b,
    const int* __restrict__ batch, float* __restrict__ out, int N, int ld) {
  int node = blockIdx.x * 4 + (threadIdx.x >> 6);
  int lane = threadIdx.x & 63;
  if (node >= N) return;
  if (node != 0 && batch[node] == batch[node - 1]) return;
  int r0 = rowptr[node], r1 = rowptr[node + 1];
  float sd = sdst[node];
  float s = 0.f;
  for (int i = r0 + lane; i < r1; i += 64) {
    float v = ssrc[csr_src[i]] + sd;
    v = v > 0.f ? v : v * NEG_ATT;
    float x = expf(v);
    alpha[i] = x;
    s += x;
  }
#pragma unroll
  for (int off = 32; off > 0; off >>= 1) s += __shfl_xor(s, off);
  float inv = 1.f / s;
  int c = lane & 15, eg = lane >> 4;
  float acc = 0.f;
  for (int i = r0 + eg; i < r1; i += 4)
    acc += alpha[i] * bf2f(Hb[(size_t)csr_src[i] * ld + c]);
#pragma unroll
  for (int off = 16; off < 64; off <<= 1) acc += __shfl_xor(acc, off);
  if (eg == 0) {
    float v = (r0 == r1) ? b[c] : acc * inv + b[c];
    out[(size_t)batch[node] * 16 + c] = v;
  }
}

extern "C" void kernel_launch(void* const* d_in, const int* in_sizes, int n_in,
                              void* d_out, int out_size, void* d_ws, size_t ws_size,
                              hipStream_t stream) {
  const float* x   = (const float*)d_in[0];
  const int* src   = (const int*)d_in[1];
  const int* dst   = (const int*)d_in[2];
  const int* batch = (const int*)d_in[3];
  const float* W1 = (const float*)d_in[4];
  const float* as1 = (const float*)d_in[5];
  const float* ad1 = (const float*)d_in[6];
  const float* b1 = (const float*)d_in[7];
  const float* W2 = (const float*)d_in[8];
  const float* as2 = (const float*)d_in[9];
  const float* ad2 = (const float*)d_in[10];
  const float* b2 = (const float*)d_in[11];
  const float* W3 = (const float*)d_in[12];
  const float* as3 = (const float*)d_in[13];
  const float* ad3 = (const float*)d_in[14];
  const float* b3 = (const float*)d_in[15];

  const int N = in_sizes[3];   // 50000 nodes
  const int E = in_sizes[1];   // 800000 edges

  char* ws = (char*)d_ws;
  size_t off = 0;
  auto alloc = [&](size_t bytes) -> void* {
    void* p = ws + off;
    off = (off + bytes + 255) & ~(size_t)255;
    return p;
  };
  short* Hb     = (short*)alloc((size_t)N * 256 * 2);
  short* Xb     = (short*)alloc((size_t)N * 512 * 2);
  float* ssrc   = (float*)alloc((size_t)N * 4);
  float* sdst   = (float*)alloc((size_t)N * 4);
  float* alpha  = (float*)alloc((size_t)E * 4);
  int* deg      = (int*)alloc((size_t)N * 4);
  int* rowptr   = (int*)alloc((size_t)(N + 1) * 4);
  int* cnt      = (int*)alloc((size_t)N * 4);
  int* csr_src  = (int*)alloc((size_t)E * 4);
  int* bsum     = (int*)alloc((size_t)1024 * 4);
  short* W1tb   = (short*)alloc((size_t)256 * 256 * 2);
  short* W2tb   = (short*)alloc((size_t)256 * 512 * 2);
  short* W3tb   = (short*)alloc((size_t)64 * 512 * 2);
  (void)ws_size;

  dim3 blk(256);
  int eblocks = (E + 255) / 256;
  int nblocks = (N + 255) / 256;
  int gblocksY = (N + 63) / 64;
  int nb4 = (N + 3) / 4;

  // ---- conversions + CSR build
  conv_w<<<(128 * 256 + 255) / 256, blk, 0, stream>>>(W1, W1tb, 128, 256);
  conv_w<<<(256 * 256 + 255) / 256, blk, 0, stream>>>(W2, W2tb, 256, 256);
  (void)hipMemsetAsync(W3tb, 0, (size_t)64 * 512 * 2, stream);
  conv_w<<<(256 * 16 + 255) / 256, blk, 0, stream>>>(W3, W3tb, 256, 16);
  conv_x<<<(int)(((long long)N * 32 + 255) / 256), blk, 0, stream>>>(x, Xb, N, 128);
  (void)hipMemsetAsync(deg, 0, (size_t)N * 4, stream);
  deg_hist<<<eblocks, blk, 0, stream>>>(dst, deg, E);
  scan_partials<<<nblocks, blk, 0, stream>>>(deg, bsum, N);
  scan_offsets<<<1, blk, 0, stream>>>(bsum, nblocks);
  scan_final<<<nblocks, blk, 0, stream>>>(deg, bsum, rowptr, N, E);
  (void)hipMemsetAsync(cnt, 0, (size_t)N * 4, stream);
  csr_place<<<eblocks, blk, 0, stream>>>(src, dst, rowptr, cnt, csr_src, E);

  // ---- layer 1: Hb = x @ W1 (bf16), scores, fused attn+agg -> Xb (bf16 split)
  gemm_bf16split<<<dim3(4, gblocksY), blk, 0, stream>>>(Xb, W1tb, Hb, N, 256, 128, 256);
  row_dots<<<nb4, blk, 0, stream>>>(Hb, as1, ad1, ssrc, sdst, N, 256, 256);
  attn_agg256<<<nb4, blk, 0, stream>>>(Hb, ssrc, sdst, rowptr, csr_src, alpha, b1, Xb, N, NEG_ACT);

  // ---- layer 2
  gemm_bf16split<<<dim3(4, gblocksY), blk, 0, stream>>>(Xb, W2tb, Hb, N, 256, 256, 256);
  row_dots<<<nb4, blk, 0, stream>>>(Hb, as2, ad2, ssrc, sdst, N, 256, 256);
  attn_agg256<<<nb4, blk, 0, stream>>>(Hb, ssrc, sdst, rowptr, csr_src, alpha, b2, Xb, N, NEG_ACT);

  // ---- layer 3: Hb[:, :64] = h2 @ W3 (padded N=64), scores, fused attn+agg -> d_out
  gemm_bf16split<<<dim3(1, gblocksY), blk, 0, stream>>>(Xb, W3tb, Hb, N, 64, 256, 64);
  row_dots<<<nb4, blk, 0, stream>>>(Hb, as3, ad3, ssrc, sdst, N, 16, 64);
  attn_agg16<<<nb4, blk, 0, stream>>>(Hb, ssrc, sdst, rowptr, csr_src, alpha, b3, batch,
                                      (float*)d_out, N, 64);
}

// Round 24
// 375.284 us; speedup vs baseline: 16.3154x; 1.0284x over previous
//
#include <hip/hip_runtime.h>

#define NEG_ATT 0.2f
#define NEG_ACT 0.01f

typedef short s16x8 __attribute__((ext_vector_type(8)));
typedef float f32x4 __attribute__((ext_vector_type(4)));

__device__ __forceinline__ short f2bf_rn(float f) {
  unsigned u = __float_as_uint(f);
  unsigned r = (u + 0x7FFFu + ((u >> 16) & 1u)) >> 16;
  return (short)r;
}
__device__ __forceinline__ float bf2f(short h) {
  return __uint_as_float(((unsigned)(unsigned short)h) << 16);
}

// ---------- convert X fp32 [M][K] -> Xb bf16 [M][2K] (hi cols 0..K-1, lo K..2K-1)
__global__ __launch_bounds__(256) void conv_x(const float* __restrict__ X,
    short* __restrict__ Xb, int M, int K) {
  long long gid = (long long)blockIdx.x * 256 + threadIdx.x;
  long long tot = (long long)M * (K / 4);
  if (gid >= tot) return;
  int row = (int)(gid / (K / 4));
  int c4 = ((int)(gid % (K / 4))) * 4;
  float4 v = *(const float4*)&X[(size_t)row * K + c4];
  short4 hi, lo;
  hi.x = f2bf_rn(v.x); lo.x = f2bf_rn(v.x - bf2f(hi.x));
  hi.y = f2bf_rn(v.y); lo.y = f2bf_rn(v.y - bf2f(hi.y));
  hi.z = f2bf_rn(v.z); lo.z = f2bf_rn(v.z - bf2f(hi.z));
  hi.w = f2bf_rn(v.w); lo.w = f2bf_rn(v.w - bf2f(hi.w));
  *(short4*)&Xb[(size_t)row * 2 * K + c4] = hi;
  *(short4*)&Xb[(size_t)row * 2 * K + K + c4] = lo;
}

// ---------- convert+transpose W fp32 [K][N] -> Wtb bf16 [N][2K]
__global__ __launch_bounds__(256) void conv_w(const float* __restrict__ W,
    short* __restrict__ Wtb, int K, int N) {
  int gid = blockIdx.x * 256 + threadIdx.x;
  if (gid >= K * N) return;
  int k = gid / N, n = gid % N;
  float v = W[(size_t)k * N + n];
  short hi = f2bf_rn(v);
  short lo = f2bf_rn(v - bf2f(hi));
  Wtb[(size_t)n * 2 * K + k] = hi;
  Wtb[(size_t)n * 2 * K + K + k] = lo;
}

// ---------- split-bf16 MFMA GEMM: Cb[M][ldc] (bf16) = X[M,K] @ W[K,N], ~fp32 internal
__global__ __launch_bounds__(256) void gemm_bf16split(const short* __restrict__ Xb,
    const short* __restrict__ Wtb, short* __restrict__ Cb, int M, int N, int K, int ldc) {
  __shared__ short sA[2][64][40];
  __shared__ short sB[2][64][40];
  const int K2 = 2 * K;
  int tid = threadIdx.x;
  int w = tid >> 6, l = tid & 63;
  int wr = w >> 1, wc = w & 1;
  int bm = blockIdx.y * 64, bn = blockIdx.x * 64;
  int sr = tid >> 2, sq = (tid & 3) * 8;

  f32x4 acc[2][2];
#pragma unroll
  for (int i = 0; i < 2; i++)
#pragma unroll
    for (int j = 0; j < 2; j++) acc[i][j] = (f32x4)0.f;

  int lrow = l & 15, k8 = (l >> 4) * 8;

  for (int k0 = 0; k0 < K; k0 += 32) {
    {
      int g = bm + sr;
      s16x8 hi = (s16x8)0, lo = (s16x8)0;
      if (g < M) {
        hi = *(const s16x8*)&Xb[(size_t)g * K2 + k0 + sq];
        lo = *(const s16x8*)&Xb[(size_t)g * K2 + K + k0 + sq];
      }
      *(s16x8*)&sA[0][sr][sq] = hi;
      *(s16x8*)&sA[1][sr][sq] = lo;
    }
    {
      int g = bn + sr;
      *(s16x8*)&sB[0][sr][sq] = *(const s16x8*)&Wtb[(size_t)g * K2 + k0 + sq];
      *(s16x8*)&sB[1][sr][sq] = *(const s16x8*)&Wtb[(size_t)g * K2 + K + k0 + sq];
    }
    __syncthreads();

    s16x8 aH[2], aL[2], bH[2], bL[2];
#pragma unroll
    for (int mt = 0; mt < 2; mt++) {
      aH[mt] = *(const s16x8*)&sA[0][wr * 32 + mt * 16 + lrow][k8];
      aL[mt] = *(const s16x8*)&sA[1][wr * 32 + mt * 16 + lrow][k8];
    }
#pragma unroll
    for (int nt = 0; nt < 2; nt++) {
      bH[nt] = *(const s16x8*)&sB[0][wc * 32 + nt * 16 + lrow][k8];
      bL[nt] = *(const s16x8*)&sB[1][wc * 32 + nt * 16 + lrow][k8];
    }
#pragma unroll
    for (int mt = 0; mt < 2; mt++)
#pragma unroll
      for (int nt = 0; nt < 2; nt++) {
        acc[mt][nt] = __builtin_amdgcn_mfma_f32_16x16x32_bf16(aH[mt], bH[nt], acc[mt][nt], 0, 0, 0);
        acc[mt][nt] = __builtin_amdgcn_mfma_f32_16x16x32_bf16(aH[mt], bL[nt], acc[mt][nt], 0, 0, 0);
        acc[mt][nt] = __builtin_amdgcn_mfma_f32_16x16x32_bf16(aL[mt], bH[nt], acc[mt][nt], 0, 0, 0);
      }
    __syncthreads();
  }

  int dcol = l & 15, drow4 = (l >> 4) * 4;
#pragma unroll
  for (int mt = 0; mt < 2; mt++)
#pragma unroll
    for (int nt = 0; nt < 2; nt++) {
      int col = bn + wc * 32 + nt * 16 + dcol;
      if (col < N) {
#pragma unroll
        for (int r = 0; r < 4; r++) {
          int row = bm + wr * 32 + mt * 16 + drow4 + r;
          if (row < M) Cb[(size_t)row * ldc + col] = f2bf_rn(acc[mt][nt][r]);
        }
      }
    }
}

// ---------- per-node attention scores from bf16 H (row stride ld, F live cols)
__global__ __launch_bounds__(256) void row_dots(const short* __restrict__ Hb,
    const float* __restrict__ a_s, const float* __restrict__ a_d,
    float* __restrict__ s_src, float* __restrict__ s_dst, int Nn, int F, int ld) {
  int node = blockIdx.x * 4 + (threadIdx.x >> 6);
  int lane = threadIdx.x & 63;
  if (node >= Nn) return;
  float ss = 0.f, sd = 0.f;
  for (int c = lane; c < F; c += 64) {
    float h = bf2f(Hb[(size_t)node * ld + c]);
    ss += h * a_s[c];
    sd += h * a_d[c];
  }
#pragma unroll
  for (int off = 32; off > 0; off >>= 1) {
    ss += __shfl_down(ss, off);
    sd += __shfl_down(sd, off);
  }
  if (lane == 0) { s_src[node] = ss; s_dst[node] = sd; }
}

// ---------- CSR build
__global__ __launch_bounds__(256) void deg_hist(const int* __restrict__ dst,
    int* __restrict__ deg, int E) {
  int e = blockIdx.x * 256 + threadIdx.x;
  if (e >= E) return;
  atomicAdd(&deg[dst[e]], 1);
}

// hierarchical scan: A) per-block sums
__global__ __launch_bounds__(256) void scan_partials(const int* __restrict__ deg,
    int* __restrict__ bsum, int N) {
  __shared__ int sdata[256];
  int i = blockIdx.x * 256 + threadIdx.x;
  sdata[threadIdx.x] = (i < N) ? deg[i] : 0;
  __syncthreads();
  for (int off = 128; off > 0; off >>= 1) {
    if (threadIdx.x < off) sdata[threadIdx.x] += sdata[threadIdx.x + off];
    __syncthreads();
  }
  if (threadIdx.x == 0) bsum[blockIdx.x] = sdata[0];
}

// B) exclusive scan of block sums (nb <= 256*k via carry loop)
__global__ __launch_bounds__(256) void scan_offsets(int* __restrict__ bsum, int nb) {
  __shared__ int sdata[256];
  __shared__ int carry;
  int tid = threadIdx.x;
  if (tid == 0) carry = 0;
  __syncthreads();
  for (int base = 0; base < nb; base += 256) {
    int idx = base + tid;
    int v = (idx < nb) ? bsum[idx] : 0;
    sdata[tid] = v;
    __syncthreads();
    for (int off = 1; off < 256; off <<= 1) {
      int t = (tid >= off) ? sdata[tid - off] : 0;
      __syncthreads();
      sdata[tid] += t;
      __syncthreads();
    }
    if (idx < nb) bsum[idx] = carry + sdata[tid] - v;
    __syncthreads();
    if (tid == 255) carry += sdata[255];
    __syncthreads();
  }
}

// C) per-block exclusive scan + block offset -> rowptr; rowptr[N]=E
__global__ __launch_bounds__(256) void scan_final(const int* __restrict__ deg,
    const int* __restrict__ bsum, int* __restrict__ rowptr, int N, int E) {
  __shared__ int sdata[256];
  int i = blockIdx.x * 256 + threadIdx.x;
  int tid = threadIdx.x;
  int v = (i < N) ? deg[i] : 0;
  sdata[tid] = v;
  __syncthreads();
  for (int off = 1; off < 256; off <<= 1) {
    int t = (tid >= off) ? sdata[tid - off] : 0;
    __syncthreads();
    sdata[tid] += t;
    __syncthreads();
  }
  if (i < N) rowptr[i] = bsum[blockIdx.x] + sdata[tid] - v;
  if (blockIdx.x == 0 && tid == 0) rowptr[N] = E;
}

__global__ __launch_bounds__(256) void csr_place(const int* __restrict__ src,
    const int* __restrict__ dst, const int* __restrict__ rowptr,
    int* __restrict__ cnt, int* __restrict__ csr_src, int E) {
  int e = blockIdx.x * 256 + threadIdx.x;
  if (e >= E) return;
  int d = dst[e];
  int pos = rowptr[d] + atomicAdd(&cnt[d], 1);
  csr_src[pos] = src[e];
}

// ---------- fused single-loop softmax+aggregation, F=256: wave per node.
// no-max softmax: out = sum(exp(v_i) h_i) / sum(exp(v_i)); exp computed inline
// (wave-redundant scalar, hidden under the 512B/wave Hb row load). No alpha buffer.
__global__ __launch_bounds__(256) void attn_agg256(const short* __restrict__ Hb,
    const float* __restrict__ ssrc, const float* __restrict__ sdst,
    const int* __restrict__ rowptr, const int* __restrict__ csr_src,
    const float* __restrict__ b, short* __restrict__ outb, int N, float slope) {
  int node = blockIdx.x * 4 + (threadIdx.x >> 6);
  int lane = threadIdx.x & 63;
  if (node >= N) return;
  int r0 = rowptr[node], r1 = rowptr[node + 1];
  float sd = sdst[node];
  int c4 = lane * 4;
  float x0 = 0.f, y0 = 0.f, z0 = 0.f, w0 = 0.f;
  float x1 = 0.f, y1 = 0.f, z1 = 0.f, w1 = 0.f;
  float s = 0.f;
  int i = r0;
  for (; i + 2 <= r1; i += 2) {
    int s0 = csr_src[i], s1 = csr_src[i + 1];
    float v0 = ssrc[s0] + sd; v0 = v0 > 0.f ? v0 : v0 * NEG_ATT;
    float v1 = ssrc[s1] + sd; v1 = v1 > 0.f ? v1 : v1 * NEG_ATT;
    float a0 = expf(v0), a1 = expf(v1);
    s += a0 + a1;
    short4 h0 = *(const short4*)&Hb[(size_t)s0 * 256 + c4];
    short4 h1 = *(const short4*)&Hb[(size_t)s1 * 256 + c4];
    x0 += a0 * bf2f(h0.x); y0 += a0 * bf2f(h0.y);
    z0 += a0 * bf2f(h0.z); w0 += a0 * bf2f(h0.w);
    x1 += a1 * bf2f(h1.x); y1 += a1 * bf2f(h1.y);
    z1 += a1 * bf2f(h1.z); w1 += a1 * bf2f(h1.w);
  }
  if (i < r1) {
    int s0 = csr_src[i];
    float v0 = ssrc[s0] + sd; v0 = v0 > 0.f ? v0 : v0 * NEG_ATT;
    float a0 = expf(v0);
    s += a0;
    short4 h0 = *(const short4*)&Hb[(size_t)s0 * 256 + c4];
    x0 += a0 * bf2f(h0.x); y0 += a0 * bf2f(h0.y);
    z0 += a0 * bf2f(h0.z); w0 += a0 * bf2f(h0.w);
  }
  float inv = 1.f / s;
  float4 bias = *(const float4*)&b[c4];
  float vx = (x0 + x1) * inv + bias.x, vy = (y0 + y1) * inv + bias.y;
  float vz = (z0 + z1) * inv + bias.z, vw = (w0 + w1) * inv + bias.w;
  if (r0 == r1) { vx = bias.x; vy = bias.y; vz = bias.z; vw = bias.w; }
  vx = vx > 0.f ? vx : vx * slope;
  vy = vy > 0.f ? vy : vy * slope;
  vz = vz > 0.f ? vz : vz * slope;
  vw = vw > 0.f ? vw : vw * slope;
  short4 hi, lo;
  hi.x = f2bf_rn(vx); lo.x = f2bf_rn(vx - bf2f(hi.x));
  hi.y = f2bf_rn(vy); lo.y = f2bf_rn(vy - bf2f(hi.y));
  hi.z = f2bf_rn(vz); lo.z = f2bf_rn(vz - bf2f(hi.z));
  hi.w = f2bf_rn(vw); lo.w = f2bf_rn(vw - bf2f(hi.w));
  *(short4*)&outb[(size_t)node * 512 + c4] = hi;
  *(short4*)&outb[(size_t)node * 512 + 256 + c4] = lo;
}

// ---------- fused single-loop softmax+aggregation, layer 3, first-of-graph only
__global__ __launch_bounds__(256) void attn_agg16(const short* __restrict__ Hb,
    const float* __restrict__ ssrc, const float* __restrict__ sdst,
    const int* __restrict__ rowptr, const int* __restrict__ csr_src,
    const float* __restrict__ b, const int* __restrict__ batch,
    float* __restrict__ out, int N, int ld) {
  int node = blockIdx.x * 4 + (threadIdx.x >> 6);
  int lane = threadIdx.x & 63;
  if (node >= N) return;
  if (node != 0 && batch[node] == batch[node - 1]) return;
  int r0 = rowptr[node], r1 = rowptr[node + 1];
  float sd = sdst[node];
  // lane = (edge slot eg, channel c); per-slot partial sums, reduce at end
  int c = lane & 15, eg = lane >> 4;
  float acc = 0.f, s = 0.f;
  for (int i = r0 + eg; i < r1; i += 4) {
    int sn = csr_src[i];
    float v = ssrc[sn] + sd;
    v = v > 0.f ? v : v * NEG_ATT;
    float a = expf(v);
    s += a;
    acc += a * bf2f(Hb[(size_t)sn * ld + c]);
  }
#pragma unroll
  for (int off = 16; off < 64; off <<= 1) {
    acc += __shfl_xor(acc, off);
    s += __shfl_xor(s, off);
  }
  if (eg == 0) {
    float v = (r0 == r1) ? b[c] : acc / s + b[c];
    out[(size_t)batch[node] * 16 + c] = v;
  }
}

extern "C" void kernel_launch(void* const* d_in, const int* in_sizes, int n_in,
                              void* d_out, int out_size, void* d_ws, size_t ws_size,
                              hipStream_t stream) {
  const float* x   = (const float*)d_in[0];
  const int* src   = (const int*)d_in[1];
  const int* dst   = (const int*)d_in[2];
  const int* batch = (const int*)d_in[3];
  const float* W1 = (const float*)d_in[4];
  const float* as1 = (const float*)d_in[5];
  const float* ad1 = (const float*)d_in[6];
  const float* b1 = (const float*)d_in[7];
  const float* W2 = (const float*)d_in[8];
  const float* as2 = (const float*)d_in[9];
  const float* ad2 = (const float*)d_in[10];
  const float* b2 = (const float*)d_in[11];
  const float* W3 = (const float*)d_in[12];
  const float* as3 = (const float*)d_in[13];
  const float* ad3 = (const float*)d_in[14];
  const float* b3 = (const float*)d_in[15];

  const int N = in_sizes[3];   // 50000 nodes
  const int E = in_sizes[1];   // 800000 edges

  char* ws = (char*)d_ws;
  size_t off = 0;
  auto alloc = [&](size_t bytes) -> void* {
    void* p = ws + off;
    off = (off + bytes + 255) & ~(size_t)255;
    return p;
  };
  short* Hb     = (short*)alloc((size_t)N * 256 * 2);
  short* Xb     = (short*)alloc((size_t)N * 512 * 2);
  float* ssrc   = (float*)alloc((size_t)N * 4);
  float* sdst   = (float*)alloc((size_t)N * 4);
  int* deg      = (int*)alloc((size_t)N * 4);
  int* rowptr   = (int*)alloc((size_t)(N + 1) * 4);
  int* cnt      = (int*)alloc((size_t)N * 4);
  int* csr_src  = (int*)alloc((size_t)E * 4);
  int* bsum     = (int*)alloc((size_t)1024 * 4);
  short* W1tb   = (short*)alloc((size_t)256 * 256 * 2);
  short* W2tb   = (short*)alloc((size_t)256 * 512 * 2);
  short* W3tb   = (short*)alloc((size_t)64 * 512 * 2);
  (void)ws_size;

  dim3 blk(256);
  int eblocks = (E + 255) / 256;
  int nblocks = (N + 255) / 256;
  int gblocksY = (N + 63) / 64;
  int nb4 = (N + 3) / 4;

  // ---- conversions + CSR build
  conv_w<<<(128 * 256 + 255) / 256, blk, 0, stream>>>(W1, W1tb, 128, 256);
  conv_w<<<(256 * 256 + 255) / 256, blk, 0, stream>>>(W2, W2tb, 256, 256);
  (void)hipMemsetAsync(W3tb, 0, (size_t)64 * 512 * 2, stream);
  conv_w<<<(256 * 16 + 255) / 256, blk, 0, stream>>>(W3, W3tb, 256, 16);
  conv_x<<<(int)(((long long)N * 32 + 255) / 256), blk, 0, stream>>>(x, Xb, N, 128);
  (void)hipMemsetAsync(deg, 0, (size_t)N * 4, stream);
  deg_hist<<<eblocks, blk, 0, stream>>>(dst, deg, E);
  scan_partials<<<nblocks, blk, 0, stream>>>(deg, bsum, N);
  scan_offsets<<<1, blk, 0, stream>>>(bsum, nblocks);
  scan_final<<<nblocks, blk, 0, stream>>>(deg, bsum, rowptr, N, E);
  (void)hipMemsetAsync(cnt, 0, (size_t)N * 4, stream);
  csr_place<<<eblocks, blk, 0, stream>>>(src, dst, rowptr, cnt, csr_src, E);

  // ---- layer 1: Hb = x @ W1 (bf16), scores, fused attn+agg -> Xb (bf16 split)
  gemm_bf16split<<<dim3(4, gblocksY), blk, 0, stream>>>(Xb, W1tb, Hb, N, 256, 128, 256);
  row_dots<<<nb4, blk, 0, stream>>>(Hb, as1, ad1, ssrc, sdst, N, 256, 256);
  attn_agg256<<<nb4, blk, 0, stream>>>(Hb, ssrc, sdst, rowptr, csr_src, b1, Xb, N, NEG_ACT);

  // ---- layer 2
  gemm_bf16split<<<dim3(4, gblocksY), blk, 0, stream>>>(Xb, W2tb, Hb, N, 256, 256, 256);
  row_dots<<<nb4, blk, 0, stream>>>(Hb, as2, ad2, ssrc, sdst, N, 256, 256);
  attn_agg256<<<nb4, blk, 0, stream>>>(Hb, ssrc, sdst, rowptr, csr_src, b2, Xb, N, NEG_ACT);

  // ---- layer 3: Hb[:, :64] = h2 @ W3 (padded N=64), scores, fused attn+agg -> d_out
  gemm_bf16split<<<dim3(1, gblocksY), blk, 0, stream>>>(Xb, W3tb, Hb, N, 64, 256, 64);
  row_dots<<<nb4, blk, 0, stream>>>(Hb, as3, ad3, ssrc, sdst, N, 16, 64);
  attn_agg16<<<nb4, blk, 0, stream>>>(Hb, ssrc, sdst, rowptr, csr_src, b3, batch,
                                      (float*)d_out, N, 64);
}